// Round 8
// baseline (353.112 us; speedup 1.0000x reference)
//
#include <hip/hip_runtime.h>
#include <hip/hip_bf16.h>
#include <cstdint>
#include <math.h>

typedef unsigned short u16;
typedef unsigned int u32;
typedef __bf16 bh;
typedef bh bh8 __attribute__((ext_vector_type(8)));
typedef float f32x4 __attribute__((ext_vector_type(4)));

#define SCALE_F 0.04419417382415922f  // 512^-0.5

__device__ __forceinline__ float bf2f(u16 u) {
    union { float f; unsigned int i; } v; v.i = ((unsigned int)u) << 16; return v.f;
}
__device__ __forceinline__ u16 f2bf(float f) {
    __hip_bfloat16 h = __float2bfloat16(f);
    return __builtin_bit_cast(u16, h);
}
__device__ __forceinline__ bh8 ld8_f32(const float* p) {
    float4 f0 = *(const float4*)p;
    float4 f1 = *(const float4*)(p + 4);
    bh8 r;
    r[0] = (bh)f0.x; r[1] = (bh)f0.y; r[2] = (bh)f0.z; r[3] = (bh)f0.w;
    r[4] = (bh)f1.x; r[5] = (bh)f1.y; r[6] = (bh)f1.z; r[7] = (bh)f1.w;
    return r;
}

// ordered-uint transforms (monotone with float order)
__device__ __forceinline__ u32 ordf(float f) {
    u32 u = __float_as_uint(f);
    return u ^ ((u32)((int)u >> 31) | 0x80000000u);
}
__device__ __forceinline__ float unordf(u32 s) {
    u32 u = (s & 0x80000000u) ? (s ^ 0x80000000u) : ~s;
    return __uint_as_float(u);
}
// 24-bit ordered value | 8-bit inverted local col idx (tie -> smaller idx wins)
__device__ __forceinline__ u32 pack_vi(float v, int inv_idx) {
    return (ordf(v) & 0xFFFFFF00u) | (u32)inv_idx;
}
__device__ __forceinline__ float unpack_v(u32 p) {
    return unordf(p & 0xFFFFFF00u);
}

// direct global->LDS 16B per lane; lds base wave-uniform (dest = base + lane*16)
__device__ __forceinline__ void gl_lds16(const u16* g, u16* l) {
    __builtin_amdgcn_global_load_lds(
        (const __attribute__((address_space(1))) void*)g,
        (__attribute__((address_space(3))) void*)l, 16, 0, 0);
}

// bijective XCD swizzle (T1): grids with NY=64 -> each XCD owns a contiguous
// 8-row y-range, y-inner order so consecutive blocks share B panels in L2.
__device__ __forceinline__ void xcd_swz(int bid, int& x, int& y) {
    int xcd = bid & 7, idx = bid >> 3;
    x = idx >> 3;
    y = xcd * 8 + (idx & 7);
}

// ---------------------------------------------------------------------------
// 6 weight transposes (fp32 [R,C] -> bf16 [C,R]) + x fp32->bf16, one dispatch
__global__ void transpose_cvt(const float* s0, u16* d0, const float* s1, u16* d1,
                              const float* s2, u16* d2, const float* s3, u16* d3,
                              const float* s4, u16* d4, const float* s5, u16* d5,
                              const float* xs, u16* xd) {
    int b = blockIdx.x;
    if (b >= 1664) {  // cvt_x part: 4096 blocks, 8 elems/thread
        int t = threadIdx.y * 32 + threadIdx.x;
        size_t i = ((size_t)(b - 1664) * 256 + t) * 8;
        *(bh8*)(xd + i) = ld8_f32(xs + i);
        return;
    }
    __shared__ float tsh[32][33];
    const float* src; u16* dst; int R, C, tt;
    if      (b < 512)  { src = s0; dst = d0; R = 1024; C = 512; tt = b; }
    else if (b < 768)  { src = s1; dst = d1; R = 512;  C = 512; tt = b - 512; }
    else if (b < 1024) { src = s2; dst = d2; R = 512;  C = 512; tt = b - 768; }
    else if (b < 1280) { src = s3; dst = d3; R = 512;  C = 512; tt = b - 1024; }
    else if (b < 1536) { src = s4; dst = d4; R = 512;  C = 512; tt = b - 1280; }
    else               { src = s5; dst = d5; R = 512;  C = 256; tt = b - 1536; }
    int ntx = C >> 5;
    int bx = (tt % ntx) * 32, by = (tt / ntx) * 32;
    int x = threadIdx.x, y = threadIdx.y;
    for (int i = 0; i < 32; i += 8)
        tsh[y + i][x] = src[(size_t)(by + y + i) * C + bx + x];
    __syncthreads();
    for (int i = 0; i < 32; i += 8)
        dst[(size_t)(bx + y + i) * R + by + x] = f2bf(tsh[x][y + i]);
}

// ---------------------------------------------------------------------------
// R10-proven 64-row K-loop (single buffer, 2 barriers/iter). High residency
// hides the drain via cross-block TLP. Used by att1 (gemm64).
template<int KT, int NF>
__device__ __forceinline__ void kloop64(const u16* __restrict__ Ag, const u16* __restrict__ Bg,
                                        u16* Alds, u16* Blds, f32x4 (&acc)[2][NF]) {
    const int tid = threadIdx.x;
    const int wave = tid >> 6, lane = tid & 63;
    const int lr = lane & 15, quad = lane >> 4;
    const int wm = (wave & 1) * 32, wn = (wave >> 1) * (NF * 16);
    const int r = tid >> 2;
    const int g8 = (((tid & 3) ^ ((tid >> 3) & 3))) * 8;   // swizzled k-block
    const int kbr8 = (quad ^ ((lr >> 1) & 3)) * 8;         // reader slot
    const u16* ga  = Ag + (size_t)r * KT + g8;
    const u16* gb0 = Bg + (size_t)r * KT + g8;
    const u16* gb1 = gb0 + (size_t)64 * KT;                // B rows 64..127 (NF=4)
    u16* la = Alds + wave * 512;   // wave-uniform
    u16* lb = Blds + wave * 512;
    #pragma unroll
    for (int k0 = 0; k0 < KT; k0 += 32) {
        __syncthreads();                 // prior reads done before LDS overwrite
        gl_lds16(ga + k0, la);
        gl_lds16(gb0 + k0, lb);
        if (NF == 4) gl_lds16(gb1 + k0, lb + 2048);
        __syncthreads();                 // drains vmcnt -> LDS writes visible
        bh8 af[2], bf_[NF];
        #pragma unroll
        for (int i = 0; i < 2; i++)
            af[i] = *(const bh8*)&Alds[(wm + i * 16 + lr) * 32 + kbr8];
        #pragma unroll
        for (int i = 0; i < NF; i++)
            bf_[i] = *(const bh8*)&Blds[(wn + i * 16 + lr) * 32 + kbr8];
        #pragma unroll
        for (int mi = 0; mi < 2; mi++)
            #pragma unroll
            for (int ni = 0; ni < NF; ni++)
                acc[mi][ni] = __builtin_amdgcn_mfma_f32_16x16x32_bf16(
                    af[mi], bf_[ni], acc[mi][ni], 0, 0, 0);
    }
}

template<int ACT, int F32OUT>
__device__ __forceinline__ void epilogue64(f32x4 (&acc)[2][2], const float* bias,
                                           float* Cf, u16* Cb, int N, int m0, int n0) {
    const int tid = threadIdx.x;
    const int wave = tid >> 6, lane = tid & 63;
    const int lr = lane & 15, quad = lane >> 4;
    const int wm = (wave & 1) * 32, wn = (wave >> 1) * 32;
    #pragma unroll
    for (int ni = 0; ni < 2; ni++) {
        int col = n0 + wn + ni * 16 + lr;
        float bs = bias[col];
        #pragma unroll
        for (int mi = 0; mi < 2; mi++) {
            #pragma unroll
            for (int i = 0; i < 4; i++) {
                int row = m0 + wm + mi * 16 + quad * 4 + i;
                float v = acc[mi][ni][i] + bs;
                if (ACT == 1) v = fmaxf(v, 0.0f);
                if (ACT == 2) v = (v > 0.0f) ? v : 0.01f * v;
                size_t o = (size_t)row * N + col;
                if (F32OUT) Cf[o] = v;
                else        Cb[o] = f2bf(v);
            }
        }
    }
}

// 64x64-tile GEMM: out = act(A @ B^T + bias). grid (N/64, M/64).
template<int ACT, int F32OUT, int KT>
__global__ __launch_bounds__(256) void gemm64(
    const u16* __restrict__ A, const u16* __restrict__ B, const float* __restrict__ bias,
    float* __restrict__ Cf, u16* __restrict__ Cb, int N)
{
    __shared__ __align__(16) u16 Alds[64 * 32];
    __shared__ __align__(16) u16 Blds[64 * 32];
    const int m0 = blockIdx.y * 64, n0 = blockIdx.x * 64;
    f32x4 acc[2][2] = {};
    kloop64<KT, 2>(A + (size_t)m0 * KT, B + (size_t)n0 * KT, Alds, Blds, acc);
    epilogue64<ACT, F32OUT>(acc, bias, Cf, Cb, N, m0, n0);
}

// ---------------------------------------------------------------------------
// 128x128-tile K-loop with counted-vmcnt pipeline (T4): 3 LDS buffers,
// prefetch depth 2, one raw s_barrier per K-step, s_waitcnt vmcnt(4).
template<int KT>
__device__ __forceinline__ void kloop128p(const u16* __restrict__ Ag,
                                          const u16* __restrict__ Bg,
                                          u16* lds, f32x4 (&acc)[4][4]) {
    const int tid = threadIdx.x;
    const int wave = tid >> 6, lane = tid & 63;
    const int lr = lane & 15, quad = lane >> 4;
    const int wm = (wave & 1) * 64, wn = (wave >> 1) * 64;
    const int r = tid >> 2;
    const int g8 = (((tid & 3) ^ ((tid >> 3) & 3))) * 8;   // swizzled k-block
    const int kbr8 = (quad ^ ((lr >> 1) & 3)) * 8;         // reader slot
    const u16* ga0 = Ag + (size_t)r * KT + g8;
    const u16* ga1 = ga0 + (size_t)64 * KT;                // A rows 64..127
    const u16* gb0 = Bg + (size_t)r * KT + g8;
    const u16* gb1 = gb0 + (size_t)64 * KT;                // B rows 64..127
    const int wofs = wave * 512;                           // wave-uniform chunk
    constexpr int NT = KT / 32;
    gl_lds16(ga0,      lds + wofs);
    gl_lds16(ga1,      lds + wofs + 2048);
    gl_lds16(gb0,      lds + 4096 + wofs);
    gl_lds16(gb1,      lds + 4096 + wofs + 2048);
    gl_lds16(ga0 + 32, lds + 8192 + wofs);
    gl_lds16(ga1 + 32, lds + 8192 + wofs + 2048);
    gl_lds16(gb0 + 32, lds + 8192 + 4096 + wofs);
    gl_lds16(gb1 + 32, lds + 8192 + 4096 + wofs + 2048);
    #pragma unroll
    for (int t = 0; t < NT; t++) {
        if (t + 1 < NT) asm volatile("s_waitcnt vmcnt(4)" ::: "memory");
        else            asm volatile("s_waitcnt vmcnt(0)" ::: "memory");
        __builtin_amdgcn_s_barrier();    // all waves' stage(t) landed
        if (t + 2 < NT) {
            const int k2 = (t + 2) * 32;
            u16* b = lds + ((t + 2) % 3) * 8192;
            gl_lds16(ga0 + k2, b + wofs);
            gl_lds16(ga1 + k2, b + wofs + 2048);
            gl_lds16(gb0 + k2, b + 4096 + wofs);
            gl_lds16(gb1 + k2, b + 4096 + wofs + 2048);
        }
        const u16* Ab = lds + (t % 3) * 8192;
        const u16* Bb = Ab + 4096;
        bh8 af[4], bf_[4];
        #pragma unroll
        for (int i = 0; i < 4; i++) {
            af[i]  = *(const bh8*)&Ab[(wm + i * 16 + lr) * 32 + kbr8];
            bf_[i] = *(const bh8*)&Bb[(wn + i * 16 + lr) * 32 + kbr8];
        }
        __builtin_amdgcn_s_setprio(1);   // T5
        #pragma unroll
        for (int mi = 0; mi < 4; mi++)
            #pragma unroll
            for (int ni = 0; ni < 4; ni++)
                acc[mi][ni] = __builtin_amdgcn_mfma_f32_16x16x32_bf16(
                    af[mi], bf_[ni], acc[mi][ni], 0, 0, 0);
        __builtin_amdgcn_s_setprio(0);
    }
    // caller must __syncthreads() before reusing LDS.
}

template<int ACT, int F32OUT>
__device__ __forceinline__ void epilogue128(f32x4 (&acc)[4][4], const float* bias,
                                            float* Cf, u16* Cb, int N, int m0, int n0) {
    const int tid = threadIdx.x;
    const int wave = tid >> 6, lane = tid & 63;
    const int lr = lane & 15, quad = lane >> 4;
    const int wm = (wave & 1) * 64, wn = (wave >> 1) * 64;
    #pragma unroll
    for (int ni = 0; ni < 4; ni++) {
        int col = n0 + wn + ni * 16 + lr;
        float bs = bias[col];
        #pragma unroll
        for (int mi = 0; mi < 4; mi++) {
            #pragma unroll
            for (int i = 0; i < 4; i++) {
                int row = m0 + wm + mi * 16 + quad * 4 + i;
                float v = acc[mi][ni][i] + bs;
                if (ACT == 1) v = fmaxf(v, 0.0f);
                if (ACT == 2) v = (v > 0.0f) ? v : 0.01f * v;
                size_t o = (size_t)row * N + col;
                if (F32OUT) Cf[o] = v;
                else        Cb[o] = f2bf(v);
            }
        }
    }
}

// 128x128-tile GEMM, XCD-swizzled grid (GNX, 64). Used for fc1 (GNX=4).
template<int ACT, int F32OUT, int KT, int GNX>
__global__ __launch_bounds__(256) void gemm128(
    const u16* __restrict__ A, const u16* __restrict__ B, const float* __restrict__ bias,
    float* __restrict__ Cf, u16* __restrict__ Cb, int N)
{
    __shared__ __align__(16) u16 ldsbuf[3 * 8192];
    int bx, by;
    xcd_swz(blockIdx.y * GNX + blockIdx.x, bx, by);
    const int m0 = by * 128, n0 = bx * 128;
    f32x4 acc[4][4] = {};
    kloop128p<KT>(A + (size_t)m0 * KT, B + (size_t)n0 * KT, ldsbuf, acc);
    epilogue128<ACT, F32OUT>(acc, bias, Cf, Cb, N, m0, n0);
}

// fused e_h / e_t on 128-tiles: grid (8, 64) XCD-swizzled; bx<4 -> wh, else wt
__global__ __launch_bounds__(256) void ehet128(
    const u16* __restrict__ A, const u16* __restrict__ Bh, const u16* __restrict__ Bt,
    const float* __restrict__ bh_, const float* __restrict__ bt_,
    u16* __restrict__ Oh, u16* __restrict__ Ot)
{
    __shared__ __align__(16) u16 ldsbuf[3 * 8192];
    int bx, by;
    xcd_swz(blockIdx.y * 8 + blockIdx.x, bx, by);
    const int m0 = by * 128, n0 = (bx & 3) * 128;
    const u16* B = (bx < 4) ? Bh : Bt;
    const float* bias = (bx < 4) ? bh_ : bt_;
    u16* O = (bx < 4) ? Oh : Ot;
    f32x4 acc[4][4] = {};
    kloop128p<512>(A + (size_t)m0 * 512, B + (size_t)n0 * 512, ldsbuf, acc);
    epilogue128<0, 0>(acc, bias, nullptr, O, 512, m0, n0);
}

// ---------------------------------------------------------------------------
// R17: fused emb = lrelu(s1@l1+b1) + lrelu(s2@l2+b2) on 128-tiles: two
// sequential counted-vmcnt kloops sharing the staging LDS.
__global__ __launch_bounds__(256) void lin12_128(
    const u16* __restrict__ A1, const u16* __restrict__ B1, const float* __restrict__ b1,
    const u16* __restrict__ A2, const u16* __restrict__ B2, const float* __restrict__ b2,
    u16* __restrict__ O)
{
    __shared__ __align__(16) u16 ldsbuf[3 * 8192];
    int bx, by;
    xcd_swz(blockIdx.y * 4 + blockIdx.x, bx, by);
    const int m0 = by * 128, n0 = bx * 128;
    f32x4 acc1[4][4] = {}, acc2[4][4] = {};
    kloop128p<512>(A1 + (size_t)m0 * 512, B1 + (size_t)n0 * 512, ldsbuf, acc1);
    __syncthreads();   // kloop1 reads done before kloop2 prologue restages buf0
    kloop128p<512>(A2 + (size_t)m0 * 512, B2 + (size_t)n0 * 512, ldsbuf, acc2);
    const int tid = threadIdx.x;
    const int wave = tid >> 6, lane = tid & 63;
    const int lr = lane & 15, quad = lane >> 4;
    const int wm = (wave & 1) * 64, wn = (wave >> 1) * 64;
    #pragma unroll
    for (int ni = 0; ni < 4; ni++) {
        int col = n0 + wn + ni * 16 + lr;
        float bs1 = b1[col], bs2 = b2[col];
        #pragma unroll
        for (int mi = 0; mi < 4; mi++) {
            #pragma unroll
            for (int i = 0; i < 4; i++) {
                int row = m0 + wm + mi * 16 + quad * 4 + i;
                float v1 = acc1[mi][ni][i] + bs1;
                v1 = (v1 > 0.0f) ? v1 : 0.01f * v1;
                float v2 = acc2[mi][ni][i] + bs2;
                v2 = (v2 > 0.0f) ? v2 : 0.01f * v2;
                O[(size_t)row * 512 + col] = f2bf(v1 + v2);
            }
        }
    }
}

// ---------------------------------------------------------------------------
// R18: 8-wave (512-thread) fused 128x256 logits K-loop. Same tile, same
// 3x24KB counted-vmcnt depth-2 schedule as R14, but 8 waves each owning a
// 64x64 sub-tile (acc[4][4] = 64 VGPR, vs 4 waves x acc[4][8] = 128). Doubles
// waves/SIMD (2 -> 4 at 2 blocks/CU) to hide the dependency stalls that held
// R14 at ~25% on every pipe. Staging = 3 x 8KB gl_lds16 per step (512 threads
// move 8KB/call) -> vmcnt(3). XOR swizzle keys invariant (row bases % 8 == 0).
template<int KT>
__device__ __forceinline__ void kloop256w8(const u16* __restrict__ Ag,
                                           const u16* __restrict__ Bg,
                                           u16* lds, f32x4 (&acc)[4][4]) {
    const int tid = threadIdx.x;
    const int wave = tid >> 6, lane = tid & 63;
    const int lr = lane & 15, quad = lane >> 4;
    const int wm = (wave & 1) * 64;          // row-half
    const int wq = wave >> 1;                // col-quarter (0..3)
    const int r = tid >> 2;                  // 0..127
    const int g8 = (((tid & 3) ^ ((tid >> 3) & 3))) * 8;   // swizzled k-block
    const int kbr8 = (quad ^ ((lr >> 1) & 3)) * 8;         // reader slot
    const u16* ga  = Ag + (size_t)r * KT + g8;             // A rows 0..127
    const u16* gb0 = Bg + (size_t)r * KT + g8;             // B rows 0..127
    const u16* gb1 = gb0 + (size_t)128 * KT;               // B rows 128..255
    const int wofs = wave * 512;             // u16: wave's 1KB stage chunk
    constexpr int NT = KT / 32;
    constexpr int BUF = 12288;               // u16: A[0,4096) B[4096,12288)
    auto stage = [&](int t, int koff) {
        u16* b = lds + (t % 3) * BUF;
        gl_lds16(ga  + koff, b + wofs);          // A 8KB in one call (8 waves)
        gl_lds16(gb0 + koff, b + 4096 + wofs);
        gl_lds16(gb1 + koff, b + 8192 + wofs);
    };
    stage(0, 0);
    stage(1, 32);
    #pragma unroll
    for (int t = 0; t < NT; t++) {
        if (t + 1 < NT) asm volatile("s_waitcnt vmcnt(3)" ::: "memory");
        else            asm volatile("s_waitcnt vmcnt(0)" ::: "memory");
        __builtin_amdgcn_s_barrier();        // all waves' stage(t) landed
        if (t + 2 < NT) stage(t + 2, (t + 2) * 32);
        const u16* Ab = lds + (t % 3) * BUF;
        const u16* Bb = Ab + 4096 + wq * 2048;   // this wave's 64 B-rows
        bh8 af[4], bf_[4];
        #pragma unroll
        for (int i = 0; i < 4; i++) {
            af[i]  = *(const bh8*)&Ab[(wm + i * 16 + lr) * 32 + kbr8];
            bf_[i] = *(const bh8*)&Bb[(i * 16 + lr) * 32 + kbr8];
        }
        __builtin_amdgcn_s_setprio(1);       // T5
        #pragma unroll
        for (int mi = 0; mi < 4; mi++)
            #pragma unroll
            for (int ni = 0; ni < 4; ni++)
                acc[mi][ni] = __builtin_amdgcn_mfma_f32_16x16x32_bf16(
                    af[mi], bf_[ni], acc[mi][ni], 0, 0, 0);
        __builtin_amdgcn_s_setprio(0);
    }
    // caller must __syncthreads() before reusing LDS.
}

// fused logits GEMM + branchless packed top-6, 512 threads. Block = 128 rows
// x 256 cols, grid (32, 64), XCD-swizzled. LDS = 72KB (3x24KB staging; 33KB
// top-k scratch S aliases it) -> 2 blocks/CU = 16 waves = 4 waves/SIMD.
// Scan: 8 threads/row (serial ins6 chain halves vs R14). tvp layout and
// topk_merge UNCHANGED.
__global__ __launch_bounds__(512, 2) void logits_topk(
    const u16* __restrict__ Ah, const u16* __restrict__ Bt, u32* __restrict__ tvp)
{
    __shared__ __align__(16) u16 ldsbuf[3 * 12288];   // 72KB
    u32* S = (u32*)ldsbuf;                            // 64*129*4 = 33KB alias
    const int tid = threadIdx.x;
    int bx, by;
    xcd_swz(blockIdx.y * 32 + blockIdx.x, bx, by);
    const int m0 = by * 128;
    const int cb0 = bx * 256;
    const int lane = tid & 63, wave = tid >> 6;
    const int wh = wave & 1;                     // row-half this wave owns
    const int wq = wave >> 1;                    // col-quarter this wave owns
    const int lr = lane & 15, quad = lane >> 4;
    const int srow = tid >> 3, scg = tid & 7;    // scan: 64 rows x 8 col-groups

    f32x4 acc[4][4] = {};
    kloop256w8<512>(Ah + (size_t)m0 * 512, Bt + (size_t)cb0 * 512, ldsbuf, acc);

    u32 v[2][6] = {{0,0,0,0,0,0},{0,0,0,0,0,0}};
    #pragma unroll
    for (int h = 0; h < 2; h++) {
        #pragma unroll
        for (int nh = 0; nh < 2; nh++) {
            __syncthreads();          // kloop / prior scan reads fully done
            if (wh == h && (wq >> 1) == nh) {     // 2 waves write their 64x64
                #pragma unroll
                for (int mi = 0; mi < 4; mi++)
                    #pragma unroll
                    for (int ni = 0; ni < 4; ni++)
                        #pragma unroll
                        for (int i = 0; i < 4; i++) {
                            int colLocal = wq * 64 + ni * 16 + lr;   // 0..255
                            S[(mi * 16 + quad * 4 + i) * 129 + (colLocal - nh * 128)]
                                = pack_vi(acc[mi][ni][i], 255 - colLocal);
                        }
            }
            __syncthreads();
            const u32* Sr = &S[srow * 129 + scg * 16];
            #pragma unroll
            for (int c = 0; c < 16; c++) {
                u32 x = Sr[c];
                v[h][5] = max(v[h][5], min(v[h][4], x));
                v[h][4] = max(v[h][4], min(v[h][3], x));
                v[h][3] = max(v[h][3], min(v[h][2], x));
                v[h][2] = max(v[h][2], min(v[h][1], x));
                v[h][1] = max(v[h][1], min(v[h][0], x));
                v[h][0] = max(v[h][0], x);
            }
        }
    }
    // merge the eight col-group lists per row through LDS, per row-half
    #pragma unroll
    for (int h = 0; h < 2; h++) {
        __syncthreads();
        {
            u32* dst = &S[srow * 129 + scg * 6];
            #pragma unroll
            for (int j = 0; j < 6; j++) dst[j] = v[h][j];
        }
        __syncthreads();
        if (tid < 64) {
            u32 m0v = 0, m1v = 0, m2v = 0, m3v = 0, m4v = 0, m5v = 0;
            const u32* Sr = &S[tid * 129];
            #pragma unroll
            for (int s = 0; s < 48; s++) {
                u32 x = Sr[s];
                m5v = max(m5v, min(m4v, x));
                m4v = max(m4v, min(m3v, x));
                m3v = max(m3v, min(m2v, x));
                m2v = max(m2v, min(m1v, x));
                m1v = max(m1v, min(m0v, x));
                m0v = max(m0v, x);
            }
            u32* dst = tvp + (size_t)(m0 + h * 64 + tid) * 192 + bx * 6;
            dst[0] = m0v; dst[1] = m1v; dst[2] = m2v;
            dst[3] = m3v; dst[4] = m4v; dst[5] = m5v;
        }
    }
}

// merge 32 packed partial top-6 lists per row -> final top-6 (fp32 val + idx)
__global__ void topk_merge(const u32* __restrict__ tvp,
                           float* __restrict__ tv, int* __restrict__ ti)
{
    int r = blockIdx.x * 64 + threadIdx.x;
    u32 v[6]; int ix[6];
    #pragma unroll
    for (int j = 0; j < 6; j++) { v[j] = 0; ix[j] = 0; }
    const u32* pv = tvp + (size_t)r * 192;
    for (int b = 0; b < 32; b++) {
        #pragma unroll
        for (int j2 = 0; j2 < 6; j2++) {
            u32 p = pv[b * 6 + j2];
            if (p <= v[5]) break;     // group is descending: rest can't insert
            v[5] = p; ix[5] = b * 256 + 255 - (int)(p & 255u);
            #pragma unroll
            for (int j = 5; j > 0; j--) {
                if (v[j] > v[j - 1]) {
                    u32 tf = v[j]; v[j] = v[j - 1]; v[j - 1] = tf;
                    int tx = ix[j]; ix[j] = ix[j - 1]; ix[j - 1] = tx;
                }
            }
        }
    }
    #pragma unroll
    for (int j = 0; j < 6; j++) {
        tv[(size_t)r * 6 + j] = unpack_v(v[j]) * SCALE_F;
        ti[(size_t)r * 6 + j] = ix[j];
    }
}

// ---------------------------------------------------------------------------
// neighbor aggregation, one WAVE per row (no block barriers). fp32 math.
__global__ __launch_bounds__(256) void neighbor_kernel(
    const u16* __restrict__ eH, const u16* __restrict__ eT,
    const float* __restrict__ tv, const int* __restrict__ ti,
    u16* __restrict__ s1, u16* __restrict__ s2)
{
    const int tid = threadIdx.x, wave = tid >> 6, lane = tid & 63;
    const int n = blockIdx.x * 4 + wave;
    float tw[6]; int id[6];
    #pragma unroll
    for (int j = 0; j < 6; j++) {
        tw[j] = tv[n * 6 + j];
        int t = ti[n * 6 + j];
        id[j] = ((unsigned)t < 8192u) ? t : 0;
    }
    float mx = tw[0];
    #pragma unroll
    for (int j = 1; j < 6; j++) mx = fmaxf(mx, tw[j]);
    float p[6]; float ps = 0.f;
    #pragma unroll
    for (int j = 0; j < 6; j++) { p[j] = __expf(tw[j] - mx); ps += p[j]; }
    float inv = 1.0f / ps;
    #pragma unroll
    for (int j = 0; j < 6; j++) p[j] *= inv;

    const size_t base = (size_t)n * 512 + lane * 8;
    float eh[8];
    { bh8 v = *(const bh8*)(eH + base);
      #pragma unroll
      for (int c = 0; c < 8; c++) eh[c] = (float)v[c]; }
    float nb[6][8];
    #pragma unroll
    for (int j = 0; j < 6; j++) {
        bh8 v = *(const bh8*)(eT + (size_t)id[j] * 512 + lane * 8);
        #pragma unroll
        for (int c = 0; c < 8; c++) nb[j][c] = (float)v[c];
    }
    float ka[6];
    #pragma unroll
    for (int j = 0; j < 6; j++) {
        float s = 0.f;
        #pragma unroll
        for (int c = 0; c < 8; c++) {
            float e = p[j] * nb[j][c] + (1.f - p[j]) * eh[c];
            float x = eh[c] + e;
            x = fminf(fmaxf(x, -15.f), 15.f);
            float ex = __expf(2.f * x);
            float g = 1.f - 2.f / (ex + 1.f);   // tanh
            s += nb[j][c] * g;
        }
        #pragma unroll
        for (int off = 32; off > 0; off >>= 1) s += __shfl_down(s, off);
        ka[j] = __shfl(s, 0);
    }
    float m2 = ka[0];
    #pragma unroll
    for (int j = 1; j < 6; j++) m2 = fmaxf(m2, ka[j]);
    float kp[6]; float ks = 0.f;
    #pragma unroll
    for (int j = 0; j < 6; j++) { kp[j] = __expf(ka[j] - m2); ks += kp[j]; }
    float inv2 = 1.0f / ks;
    #pragma unroll
    for (int j = 0; j < 6; j++) kp[j] *= inv2;
    bh8 o1, o2;
    #pragma unroll
    for (int c = 0; c < 8; c++) {
        float eN = 0.f;
        #pragma unroll
        for (int j = 0; j < 6; j++) eN += kp[j] * nb[j][c];
        o1[c] = (bh)(eh[c] + eN);
        o2[c] = (bh)(eh[c] * eN);
    }
    *(bh8*)(s1 + base) = o1;
    *(bh8*)(s2 + base) = o2;
}

// ---------------------------------------------------------------------------
__global__ void colsum_kernel(const u16* __restrict__ h, float* __restrict__ colsum) {
    int tid = threadIdx.x;
    int n0 = blockIdx.x * 32;
    float a0 = 0.f, a1 = 0.f;
    for (int k = 0; k < 32; k++) {
        size_t b = (size_t)(n0 + k) * 512;
        a0 += bf2f(h[b + tid]); a1 += bf2f(h[b + tid + 256]);
    }
    atomicAdd(&colsum[tid], a0);
    atomicAdd(&colsum[tid + 256], a1);
}

__global__ void meanmix_kernel(u16* __restrict__ h, const float* __restrict__ colsum) {
    size_t i = ((size_t)blockIdx.x * 256 + threadIdx.x) * 8;
    int col = (int)(i & 511);
    union { int4 v; u16 s[8]; } u;
    u.v = *(const int4*)&h[i];
    #pragma unroll
    for (int j = 0; j < 8; j++)
        u.s[j] = f2bf((bf2f(u.s[j]) + colsum[col + j] * (1.0f / 8192.0f)) * 0.5f);
    *(int4*)&h[i] = u.v;
}

__global__ __launch_bounds__(256) void att2_kernel(
    const float* __restrict__ a1, const float* __restrict__ w,
    const float* __restrict__ b, float* __restrict__ att)
{
    int row = blockIdx.x * 4 + (threadIdx.x >> 6);
    int lane = threadIdx.x & 63;
    const float* pr = a1 + (size_t)row * 256;
    float s = 0.f;
    #pragma unroll
    for (int k = 0; k < 4; k++) { int c = lane + k * 64; s += pr[c] * w[c]; }
    #pragma unroll
    for (int off = 32; off > 0; off >>= 1) s += __shfl_down(s, off);
    if (lane == 0) att[row] = s + b[0];
}

// parallel softmax stats: ordered-u32 atomicMax, then atomicAdd of exp sums
__global__ void att_max(const float* __restrict__ att, u32* __restrict__ scal_u) {
    int i = blockIdx.x * 256 + threadIdx.x;
    int lane = threadIdx.x & 63;
    u32 o = ordf(att[i]);
    #pragma unroll
    for (int off = 32; off > 0; off >>= 1) o = max(o, (u32)__shfl_down((int)o, off));
    if (lane == 0) atomicMax(&scal_u[0], o);
}
__global__ void att_sum(const float* __restrict__ att, float* __restrict__ scal) {
    int i = blockIdx.x * 256 + threadIdx.x;
    int lane = threadIdx.x & 63;
    float mx = unordf(((const u32*)scal)[0]);
    float e = __expf(att[i] - mx);
    #pragma unroll
    for (int off = 32; off > 0; off >>= 1) e += __shfl_down(e, off);
    if (lane == 0) atomicAdd(&scal[1], e);
}

__global__ void pooled_kernel(const u16* __restrict__ emb, const float* __restrict__ att,
                              const float* __restrict__ scal, float* __restrict__ pooled) {
    int tid = threadIdx.x;
    int n0 = blockIdx.x * 32;
    float mx = unordf(((const u32*)scal)[0]);
    float inv = 1.0f / scal[1];
    float a0 = 0.f, a1 = 0.f;
    for (int k = 0; k < 32; k++) {
        int n = n0 + k;
        float w = __expf(att[n] - mx) * inv;
        size_t b = (size_t)n * 512;
        a0 += w * bf2f(emb[b + tid]);
        a1 += w * bf2f(emb[b + tid + 256]);
    }
    atomicAdd(&pooled[tid], a0);
    atomicAdd(&pooled[tid + 256], a1);
}

__global__ void final_kernel(const float* __restrict__ pooled,
                             const float* __restrict__ g, const float* __restrict__ bln,
                             const float* __restrict__ fcw, const float* __restrict__ fcb,
                             float* __restrict__ out) {
    __shared__ float red[256];
    int tid = threadIdx.x;
    float x0 = pooled[tid], x1 = pooled[tid + 256];
    red[tid] = x0 + x1; __syncthreads();
    for (int s = 128; s > 0; s >>= 1) { if (tid < s) red[tid] += red[tid + s]; __syncthreads(); }
    float mu = red[0] * (1.0f / 512.0f); __syncthreads();
    float d0 = x0 - mu, d1 = x1 - mu;
    red[tid] = d0 * d0 + d1 * d1; __syncthreads();
    for (int s = 128; s > 0; s >>= 1) { if (tid < s) red[tid] += red[tid + s]; __syncthreads(); }
    float var = red[0] * (1.0f / 512.0f); __syncthreads();
    float rstd = rsqrtf(var + 1e-5f);
    float l0 = d0 * rstd * g[tid]       + bln[tid];
    float l1 = d1 * rstd * g[tid + 256] + bln[tid + 256];
    red[tid] = l0 * fcw[tid * 2] + l1 * fcw[(tid + 256) * 2]; __syncthreads();
    for (int s = 128; s > 0; s >>= 1) { if (tid < s) red[tid] += red[tid + s]; __syncthreads(); }
    float o0 = red[0] + fcb[0]; __syncthreads();
    red[tid] = l0 * fcw[tid * 2 + 1] + l1 * fcw[(tid + 256) * 2 + 1]; __syncthreads();
    for (int s = 128; s > 0; s >>= 1) { if (tid < s) red[tid] += red[tid + s]; __syncthreads(); }
    float o1 = red[0] + fcb[1];
    if (tid == 0) {
        float m = fmaxf(o0, o1);
        float e0 = expf(o0 - m), e1 = expf(o1 - m);
        float se = e0 + e1;
        out[0] = o0;
        out[1] = o1;
        out[2] = e0 / se;
        out[3] = e1 / se;
        out[4] = (o0 >= o1) ? 0.0f : 1.0f;
    }
}

// ---------------------------------------------------------------------------
extern "C" void kernel_launch(void* const* d_in, const int* in_sizes, int n_in,
                              void* d_out, int out_size, void* d_ws, size_t ws_size,
                              hipStream_t stream)
{
    const float* x      = (const float*)d_in[0];
    const float* fc1_w  = (const float*)d_in[1];
    const float* fc1_b  = (const float*)d_in[2];
    const float* wh_w   = (const float*)d_in[3];
    const float* wh_b   = (const float*)d_in[4];
    const float* wt_w   = (const float*)d_in[5];
    const float* wt_b   = (const float*)d_in[6];
    const float* lin1_w = (const float*)d_in[7];
    const float* lin1_b = (const float*)d_in[8];
    const float* lin2_w = (const float*)d_in[9];
    const float* lin2_b = (const float*)d_in[10];
    const float* att1_w = (const float*)d_in[11];
    const float* att1_b = (const float*)d_in[12];
    const float* att2_w = (const float*)d_in[13];
    const float* att2_b = (const float*)d_in[14];
    const float* ln_g   = (const float*)d_in[15];
    const float* ln_b   = (const float*)d_in[16];
    const float* fc_w   = (const float*)d_in[17];
    const float* fc_b   = (const float*)d_in[18];
    float* out = (float*)d_out;
    char* ws = (char*)d_ws;

    u16*   fc1T   = (u16*)(ws + 0);
    u16*   whT    = (u16*)(ws + 1048576);
    u16*   wtT    = (u16*)(ws + 1572864);
    u16*   l1T    = (u16*)(ws + 2097152);
    u16*   l2T    = (u16*)(ws + 2621440);
    u16*   a1T    = (u16*)(ws + 3145728);
    float* tv     = (float*)(ws + 3407872);
    int*   ti     = (int*)(ws + 3604480);
    float* att    = (float*)(ws + 3801088);
    float* colsum = (float*)(ws + 3833856);
    float* pooled = (float*)(ws + 3835904);
    float* scal   = (float*)(ws + 3837952);
    u32*   tvp    = (u32*)(ws + 4194304);
    u16*   hbf    = (u16*)(ws + 14680064);   // 8 MB  [h; later s1]
    u16*   ehbf   = (u16*)(ws + 23068672);   // 8 MB  [e_h; later a1 fp32]
    u16*   etbf   = (u16*)(ws + 31457280);   // 8 MB  [e_t; later emb]
    u16*   s2bf   = (u16*)(ws + 39845888);   // 8 MB  [s2]
    u16*   xbf    = (u16*)(ws + 23068672);   // 16 MB (x bf16; dead after fc1)
    float* a1f    = (float*)(ws + 23068672); // 8 MB fp32 (after e_h dead)

    transpose_cvt<<<5760, dim3(32, 8), 0, stream>>>(
        fc1_w, fc1T, wh_w, whT, wt_w, wtT, lin1_w, l1T, lin2_w, l2T, att1_w, a1T, x, xbf);
    hipMemsetAsync(colsum, 0, 4160, stream);   // colsum + pooled + scal

    gemm128<1, 0, 1024, 4><<<dim3(4, 64), 256, 0, stream>>>(xbf, fc1T, fc1_b, nullptr, hbf, 512);
    colsum_kernel<<<256, 256, 0, stream>>>(hbf, colsum);
    meanmix_kernel<<<2048, 256, 0, stream>>>(hbf, colsum);

    ehet128<<<dim3(8, 64), 256, 0, stream>>>(hbf, whT, wtT, wh_b, wt_b, ehbf, etbf);

    logits_topk<<<dim3(32, 64), 512, 0, stream>>>(ehbf, etbf, tvp);
    topk_merge<<<128, 64, 0, stream>>>(tvp, tv, ti);

    neighbor_kernel<<<2048, 256, 0, stream>>>(ehbf, etbf, tv, ti, hbf, s2bf);

    lin12_128<<<dim3(4, 64), 256, 0, stream>>>(hbf, l1T, lin1_b, s2bf, l2T, lin2_b, etbf);

    gemm64<2, 1, 512><<<dim3(4, 128), 256, 0, stream>>>(etbf, a1T, att1_b, a1f, nullptr, 256);
    att2_kernel<<<2048, 256, 0, stream>>>(a1f, att2_w, att2_b, att);
    att_max<<<32, 256, 0, stream>>>(att, (u32*)scal);
    att_sum<<<32, 256, 0, stream>>>(att, scal);
    pooled_kernel<<<256, 256, 0, stream>>>(etbf, att, scal, pooled);

    final_kernel<<<1, 256, 0, stream>>>(pooled, ln_g, ln_b, fc_w, fc_b, out);
}

// Round 9
// 346.546 us; speedup vs baseline: 1.0189x; 1.0189x over previous
//
#include <hip/hip_runtime.h>
#include <hip/hip_bf16.h>
#include <cstdint>
#include <math.h>

typedef unsigned short u16;
typedef unsigned int u32;
typedef __bf16 bh;
typedef bh bh8 __attribute__((ext_vector_type(8)));
typedef float f32x4 __attribute__((ext_vector_type(4)));

#define SCALE_F 0.04419417382415922f  // 512^-0.5

__device__ __forceinline__ float bf2f(u16 u) {
    union { float f; unsigned int i; } v; v.i = ((unsigned int)u) << 16; return v.f;
}
__device__ __forceinline__ u16 f2bf(float f) {
    __hip_bfloat16 h = __float2bfloat16(f);
    return __builtin_bit_cast(u16, h);
}
__device__ __forceinline__ bh8 ld8_f32(const float* p) {
    float4 f0 = *(const float4*)p;
    float4 f1 = *(const float4*)(p + 4);
    bh8 r;
    r[0] = (bh)f0.x; r[1] = (bh)f0.y; r[2] = (bh)f0.z; r[3] = (bh)f0.w;
    r[4] = (bh)f1.x; r[5] = (bh)f1.y; r[6] = (bh)f1.z; r[7] = (bh)f1.w;
    return r;
}

// ordered-uint transforms (monotone with float order)
__device__ __forceinline__ u32 ordf(float f) {
    u32 u = __float_as_uint(f);
    return u ^ ((u32)((int)u >> 31) | 0x80000000u);
}
__device__ __forceinline__ float unordf(u32 s) {
    u32 u = (s & 0x80000000u) ? (s ^ 0x80000000u) : ~s;
    return __uint_as_float(u);
}
// 24-bit ordered value | 8-bit inverted local col idx (tie -> smaller idx wins)
__device__ __forceinline__ u32 pack_vi(float v, int inv_idx) {
    return (ordf(v) & 0xFFFFFF00u) | (u32)inv_idx;
}
__device__ __forceinline__ float unpack_v(u32 p) {
    return unordf(p & 0xFFFFFF00u);
}

// direct global->LDS 16B per lane; lds base wave-uniform (dest = base + lane*16)
__device__ __forceinline__ void gl_lds16(const u16* g, u16* l) {
    __builtin_amdgcn_global_load_lds(
        (const __attribute__((address_space(1))) void*)g,
        (__attribute__((address_space(3))) void*)l, 16, 0, 0);
}

// bijective XCD swizzle (T1), NY=64 grids: each XCD owns 8 consecutive
// y-rows, y-inner order so consecutive blocks share B panels in L2.
__device__ __forceinline__ void xcd_swz(int bid, int& x, int& y) {
    int xcd = bid & 7, idx = bid >> 3;
    x = idx >> 3;
    y = xcd * 8 + (idx & 7);
}
// NY=128 variant: each XCD owns 16 consecutive y-rows.
__device__ __forceinline__ void xcd_swz128(int bid, int& x, int& y) {
    int xcd = bid & 7, idx = bid >> 3;
    x = idx >> 4;
    y = xcd * 16 + (idx & 15);
}

// ---------------------------------------------------------------------------
// 6 weight transposes (fp32 [R,C] -> bf16 [C,R]) + x fp32->bf16, one dispatch
__global__ void transpose_cvt(const float* s0, u16* d0, const float* s1, u16* d1,
                              const float* s2, u16* d2, const float* s3, u16* d3,
                              const float* s4, u16* d4, const float* s5, u16* d5,
                              const float* xs, u16* xd) {
    int b = blockIdx.x;
    if (b >= 1664) {  // cvt_x part: 4096 blocks, 8 elems/thread
        int t = threadIdx.y * 32 + threadIdx.x;
        size_t i = ((size_t)(b - 1664) * 256 + t) * 8;
        *(bh8*)(xd + i) = ld8_f32(xs + i);
        return;
    }
    __shared__ float tsh[32][33];
    const float* src; u16* dst; int R, C, tt;
    if      (b < 512)  { src = s0; dst = d0; R = 1024; C = 512; tt = b; }
    else if (b < 768)  { src = s1; dst = d1; R = 512;  C = 512; tt = b - 512; }
    else if (b < 1024) { src = s2; dst = d2; R = 512;  C = 512; tt = b - 768; }
    else if (b < 1280) { src = s3; dst = d3; R = 512;  C = 512; tt = b - 1024; }
    else if (b < 1536) { src = s4; dst = d4; R = 512;  C = 512; tt = b - 1280; }
    else               { src = s5; dst = d5; R = 512;  C = 256; tt = b - 1536; }
    int ntx = C >> 5;
    int bx = (tt % ntx) * 32, by = (tt / ntx) * 32;
    int x = threadIdx.x, y = threadIdx.y;
    for (int i = 0; i < 32; i += 8)
        tsh[y + i][x] = src[(size_t)(by + y + i) * C + bx + x];
    __syncthreads();
    for (int i = 0; i < 32; i += 8)
        dst[(size_t)(bx + y + i) * R + by + x] = f2bf(tsh[x][y + i]);
}

// ---------------------------------------------------------------------------
// R10-proven 64-row K-loop (single buffer, 2 barriers/iter). High residency
// hides the drain via cross-block TLP. Used by att1 (gemm64).
template<int KT, int NF>
__device__ __forceinline__ void kloop64(const u16* __restrict__ Ag, const u16* __restrict__ Bg,
                                        u16* Alds, u16* Blds, f32x4 (&acc)[2][NF]) {
    const int tid = threadIdx.x;
    const int wave = tid >> 6, lane = tid & 63;
    const int lr = lane & 15, quad = lane >> 4;
    const int wm = (wave & 1) * 32, wn = (wave >> 1) * (NF * 16);
    const int r = tid >> 2;
    const int g8 = (((tid & 3) ^ ((tid >> 3) & 3))) * 8;   // swizzled k-block
    const int kbr8 = (quad ^ ((lr >> 1) & 3)) * 8;         // reader slot
    const u16* ga  = Ag + (size_t)r * KT + g8;
    const u16* gb0 = Bg + (size_t)r * KT + g8;
    const u16* gb1 = gb0 + (size_t)64 * KT;                // B rows 64..127 (NF=4)
    u16* la = Alds + wave * 512;   // wave-uniform
    u16* lb = Blds + wave * 512;
    #pragma unroll
    for (int k0 = 0; k0 < KT; k0 += 32) {
        __syncthreads();                 // prior reads done before LDS overwrite
        gl_lds16(ga + k0, la);
        gl_lds16(gb0 + k0, lb);
        if (NF == 4) gl_lds16(gb1 + k0, lb + 2048);
        __syncthreads();                 // drains vmcnt -> LDS writes visible
        bh8 af[2], bf_[NF];
        #pragma unroll
        for (int i = 0; i < 2; i++)
            af[i] = *(const bh8*)&Alds[(wm + i * 16 + lr) * 32 + kbr8];
        #pragma unroll
        for (int i = 0; i < NF; i++)
            bf_[i] = *(const bh8*)&Blds[(wn + i * 16 + lr) * 32 + kbr8];
        #pragma unroll
        for (int mi = 0; mi < 2; mi++)
            #pragma unroll
            for (int ni = 0; ni < NF; ni++)
                acc[mi][ni] = __builtin_amdgcn_mfma_f32_16x16x32_bf16(
                    af[mi], bf_[ni], acc[mi][ni], 0, 0, 0);
    }
}

template<int ACT, int F32OUT>
__device__ __forceinline__ void epilogue64(f32x4 (&acc)[2][2], const float* bias,
                                           float* Cf, u16* Cb, int N, int m0, int n0) {
    const int tid = threadIdx.x;
    const int wave = tid >> 6, lane = tid & 63;
    const int lr = lane & 15, quad = lane >> 4;
    const int wm = (wave & 1) * 32, wn = (wave >> 1) * 32;
    #pragma unroll
    for (int ni = 0; ni < 2; ni++) {
        int col = n0 + wn + ni * 16 + lr;
        float bs = bias[col];
        #pragma unroll
        for (int mi = 0; mi < 2; mi++) {
            #pragma unroll
            for (int i = 0; i < 4; i++) {
                int row = m0 + wm + mi * 16 + quad * 4 + i;
                float v = acc[mi][ni][i] + bs;
                if (ACT == 1) v = fmaxf(v, 0.0f);
                if (ACT == 2) v = (v > 0.0f) ? v : 0.01f * v;
                size_t o = (size_t)row * N + col;
                if (F32OUT) Cf[o] = v;
                else        Cb[o] = f2bf(v);
            }
        }
    }
}

// 64x64-tile GEMM: out = act(A @ B^T + bias). grid (N/64, M/64).
template<int ACT, int F32OUT, int KT>
__global__ __launch_bounds__(256) void gemm64(
    const u16* __restrict__ A, const u16* __restrict__ B, const float* __restrict__ bias,
    float* __restrict__ Cf, u16* __restrict__ Cb, int N)
{
    __shared__ __align__(16) u16 Alds[64 * 32];
    __shared__ __align__(16) u16 Blds[64 * 32];
    const int m0 = blockIdx.y * 64, n0 = blockIdx.x * 64;
    f32x4 acc[2][2] = {};
    kloop64<KT, 2>(A + (size_t)m0 * KT, B + (size_t)n0 * KT, Alds, Blds, acc);
    epilogue64<ACT, F32OUT>(acc, bias, Cf, Cb, N, m0, n0);
}

// ---------------------------------------------------------------------------
// R19: 64x128-tile counted-vmcnt K-loop. A 64x32 + B 128x32 per step =
// 3 gl_lds16; 3 x 12KB buffers = 36KB -> 4 blocks/CU (16 waves/CU) AND the
// depth-2 pipeline. acc[2][4] = 32 VGPR. Fixes the 1-block/CU starvation of
// fc1/lin12 (grid 256 blocks at 128x128 tiles = 1 wave/SIMD, zero TLP).
// XOR swizzle keys invariant (all fragment row bases % 8 == 0).
template<int KT>
__device__ __forceinline__ void kloop64w128(const u16* __restrict__ Ag,
                                            const u16* __restrict__ Bg,
                                            u16* lds, f32x4 (&acc)[2][4]) {
    const int tid = threadIdx.x;
    const int wave = tid >> 6, lane = tid & 63;
    const int lr = lane & 15, quad = lane >> 4;
    const int wm = (wave & 1) * 32, wn = (wave >> 1) * 64;
    const int r = tid >> 2;                                // 0..63
    const int g8 = (((tid & 3) ^ ((tid >> 3) & 3))) * 8;   // swizzled k-block
    const int kbr8 = (quad ^ ((lr >> 1) & 3)) * 8;         // reader slot
    const u16* ga  = Ag + (size_t)r * KT + g8;             // A rows 0..63
    const u16* gb0 = Bg + (size_t)r * KT + g8;             // B rows 0..63
    const u16* gb1 = gb0 + (size_t)64 * KT;                // B rows 64..127
    const int wofs = wave * 512;                           // wave's 1KB chunk
    constexpr int NT = KT / 32;
    constexpr int BUF = 6144;    // u16 per buffer: A[0,2048) B[2048,6144)
    auto stage = [&](int t, int koff) {
        u16* b = lds + (t % 3) * BUF;
        gl_lds16(ga  + koff, b + wofs);
        gl_lds16(gb0 + koff, b + 2048 + wofs);
        gl_lds16(gb1 + koff, b + 4096 + wofs);
    };
    stage(0, 0);
    stage(1, 32);
    #pragma unroll
    for (int t = 0; t < NT; t++) {
        if (t + 1 < NT) asm volatile("s_waitcnt vmcnt(3)" ::: "memory");
        else            asm volatile("s_waitcnt vmcnt(0)" ::: "memory");
        __builtin_amdgcn_s_barrier();    // all waves' stage(t) landed
        if (t + 2 < NT) stage(t + 2, (t + 2) * 32);
        const u16* Ab = lds + (t % 3) * BUF;
        const u16* Bb = Ab + 2048;
        bh8 af[2], bf_[4];
        #pragma unroll
        for (int i = 0; i < 2; i++)
            af[i] = *(const bh8*)&Ab[(wm + i * 16 + lr) * 32 + kbr8];
        #pragma unroll
        for (int i = 0; i < 4; i++)
            bf_[i] = *(const bh8*)&Bb[(wn + i * 16 + lr) * 32 + kbr8];
        __builtin_amdgcn_s_setprio(1);   // T5
        #pragma unroll
        for (int mi = 0; mi < 2; mi++)
            #pragma unroll
            for (int ni = 0; ni < 4; ni++)
                acc[mi][ni] = __builtin_amdgcn_mfma_f32_16x16x32_bf16(
                    af[mi], bf_[ni], acc[mi][ni], 0, 0, 0);
        __builtin_amdgcn_s_setprio(0);
    }
    // caller must __syncthreads() before reusing LDS.
}

template<int ACT, int F32OUT>
__device__ __forceinline__ void epilogue64x128(f32x4 (&acc)[2][4], const float* bias,
                                               float* Cf, u16* Cb, int N, int m0, int n0) {
    const int tid = threadIdx.x;
    const int wave = tid >> 6, lane = tid & 63;
    const int lr = lane & 15, quad = lane >> 4;
    const int wm = (wave & 1) * 32, wn = (wave >> 1) * 64;
    #pragma unroll
    for (int ni = 0; ni < 4; ni++) {
        int col = n0 + wn + ni * 16 + lr;
        float bs = bias[col];
        #pragma unroll
        for (int mi = 0; mi < 2; mi++) {
            #pragma unroll
            for (int i = 0; i < 4; i++) {
                int row = m0 + wm + mi * 16 + quad * 4 + i;
                float v = acc[mi][ni][i] + bs;
                if (ACT == 1) v = fmaxf(v, 0.0f);
                if (ACT == 2) v = (v > 0.0f) ? v : 0.01f * v;
                size_t o = (size_t)row * N + col;
                if (F32OUT) Cf[o] = v;
                else        Cb[o] = f2bf(v);
            }
        }
    }
}

// 64x128-tile GEMM, XCD-swizzled grid (GNX, 128). Used for fc1 (GNX=4).
template<int ACT, int F32OUT, int KT, int GNX>
__global__ __launch_bounds__(256) void gemm64x128(
    const u16* __restrict__ A, const u16* __restrict__ B, const float* __restrict__ bias,
    float* __restrict__ Cf, u16* __restrict__ Cb, int N)
{
    __shared__ __align__(16) u16 ldsbuf[3 * 6144];
    int bx, by;
    xcd_swz128(blockIdx.y * GNX + blockIdx.x, bx, by);
    const int m0 = by * 64, n0 = bx * 128;
    f32x4 acc[2][4] = {};
    kloop64w128<KT>(A + (size_t)m0 * KT, B + (size_t)n0 * KT, ldsbuf, acc);
    epilogue64x128<ACT, F32OUT>(acc, bias, Cf, Cb, N, m0, n0);
}

// fused emb = lrelu(s1@l1+b1) + lrelu(s2@l2+b2): two sequential 64x128
// counted-vmcnt kloops, grid (4, 128) = 512 blocks -> 4 blocks/CU.
__global__ __launch_bounds__(256) void lin12_64x128(
    const u16* __restrict__ A1, const u16* __restrict__ B1, const float* __restrict__ b1,
    const u16* __restrict__ A2, const u16* __restrict__ B2, const float* __restrict__ b2,
    u16* __restrict__ O)
{
    __shared__ __align__(16) u16 ldsbuf[3 * 6144];
    int bx, by;
    xcd_swz128(blockIdx.y * 4 + blockIdx.x, bx, by);
    const int m0 = by * 64, n0 = bx * 128;
    f32x4 acc1[2][4] = {}, acc2[2][4] = {};
    kloop64w128<512>(A1 + (size_t)m0 * 512, B1 + (size_t)n0 * 512, ldsbuf, acc1);
    __syncthreads();   // kloop1 reads done before kloop2 prologue restages buf0
    kloop64w128<512>(A2 + (size_t)m0 * 512, B2 + (size_t)n0 * 512, ldsbuf, acc2);
    const int tid = threadIdx.x;
    const int wave = tid >> 6, lane = tid & 63;
    const int lr = lane & 15, quad = lane >> 4;
    const int wm = (wave & 1) * 32, wn = (wave >> 1) * 64;
    #pragma unroll
    for (int ni = 0; ni < 4; ni++) {
        int col = n0 + wn + ni * 16 + lr;
        float bs1 = b1[col], bs2 = b2[col];
        #pragma unroll
        for (int mi = 0; mi < 2; mi++) {
            #pragma unroll
            for (int i = 0; i < 4; i++) {
                int row = m0 + wm + mi * 16 + quad * 4 + i;
                float v1 = acc1[mi][ni][i] + bs1;
                v1 = (v1 > 0.0f) ? v1 : 0.01f * v1;
                float v2 = acc2[mi][ni][i] + bs2;
                v2 = (v2 > 0.0f) ? v2 : 0.01f * v2;
                O[(size_t)row * 512 + col] = f2bf(v1 + v2);
            }
        }
    }
}

// ---------------------------------------------------------------------------
// 128x128-tile K-loop with counted-vmcnt pipeline (T4): 3 LDS buffers,
// prefetch depth 2, one raw s_barrier per K-step, s_waitcnt vmcnt(4).
template<int KT>
__device__ __forceinline__ void kloop128p(const u16* __restrict__ Ag,
                                          const u16* __restrict__ Bg,
                                          u16* lds, f32x4 (&acc)[4][4]) {
    const int tid = threadIdx.x;
    const int wave = tid >> 6, lane = tid & 63;
    const int lr = lane & 15, quad = lane >> 4;
    const int wm = (wave & 1) * 64, wn = (wave >> 1) * 64;
    const int r = tid >> 2;
    const int g8 = (((tid & 3) ^ ((tid >> 3) & 3))) * 8;   // swizzled k-block
    const int kbr8 = (quad ^ ((lr >> 1) & 3)) * 8;         // reader slot
    const u16* ga0 = Ag + (size_t)r * KT + g8;
    const u16* ga1 = ga0 + (size_t)64 * KT;                // A rows 64..127
    const u16* gb0 = Bg + (size_t)r * KT + g8;
    const u16* gb1 = gb0 + (size_t)64 * KT;                // B rows 64..127
    const int wofs = wave * 512;                           // wave-uniform chunk
    constexpr int NT = KT / 32;
    gl_lds16(ga0,      lds + wofs);
    gl_lds16(ga1,      lds + wofs + 2048);
    gl_lds16(gb0,      lds + 4096 + wofs);
    gl_lds16(gb1,      lds + 4096 + wofs + 2048);
    gl_lds16(ga0 + 32, lds + 8192 + wofs);
    gl_lds16(ga1 + 32, lds + 8192 + wofs + 2048);
    gl_lds16(gb0 + 32, lds + 8192 + 4096 + wofs);
    gl_lds16(gb1 + 32, lds + 8192 + 4096 + wofs + 2048);
    #pragma unroll
    for (int t = 0; t < NT; t++) {
        if (t + 1 < NT) asm volatile("s_waitcnt vmcnt(4)" ::: "memory");
        else            asm volatile("s_waitcnt vmcnt(0)" ::: "memory");
        __builtin_amdgcn_s_barrier();    // all waves' stage(t) landed
        if (t + 2 < NT) {
            const int k2 = (t + 2) * 32;
            u16* b = lds + ((t + 2) % 3) * 8192;
            gl_lds16(ga0 + k2, b + wofs);
            gl_lds16(ga1 + k2, b + wofs + 2048);
            gl_lds16(gb0 + k2, b + 4096 + wofs);
            gl_lds16(gb1 + k2, b + 4096 + wofs + 2048);
        }
        const u16* Ab = lds + (t % 3) * 8192;
        const u16* Bb = Ab + 4096;
        bh8 af[4], bf_[4];
        #pragma unroll
        for (int i = 0; i < 4; i++) {
            af[i]  = *(const bh8*)&Ab[(wm + i * 16 + lr) * 32 + kbr8];
            bf_[i] = *(const bh8*)&Bb[(wn + i * 16 + lr) * 32 + kbr8];
        }
        __builtin_amdgcn_s_setprio(1);   // T5
        #pragma unroll
        for (int mi = 0; mi < 4; mi++)
            #pragma unroll
            for (int ni = 0; ni < 4; ni++)
                acc[mi][ni] = __builtin_amdgcn_mfma_f32_16x16x32_bf16(
                    af[mi], bf_[ni], acc[mi][ni], 0, 0, 0);
        __builtin_amdgcn_s_setprio(0);
    }
    // caller must __syncthreads() before reusing LDS.
}

template<int ACT, int F32OUT>
__device__ __forceinline__ void epilogue128(f32x4 (&acc)[4][4], const float* bias,
                                            float* Cf, u16* Cb, int N, int m0, int n0) {
    const int tid = threadIdx.x;
    const int wave = tid >> 6, lane = tid & 63;
    const int lr = lane & 15, quad = lane >> 4;
    const int wm = (wave & 1) * 64, wn = (wave >> 1) * 64;
    #pragma unroll
    for (int ni = 0; ni < 4; ni++) {
        int col = n0 + wn + ni * 16 + lr;
        float bs = bias[col];
        #pragma unroll
        for (int mi = 0; mi < 4; mi++) {
            #pragma unroll
            for (int i = 0; i < 4; i++) {
                int row = m0 + wm + mi * 16 + quad * 4 + i;
                float v = acc[mi][ni][i] + bs;
                if (ACT == 1) v = fmaxf(v, 0.0f);
                if (ACT == 2) v = (v > 0.0f) ? v : 0.01f * v;
                size_t o = (size_t)row * N + col;
                if (F32OUT) Cf[o] = v;
                else        Cb[o] = f2bf(v);
            }
        }
    }
}

// fused e_h / e_t on 128-tiles: grid (8, 64) XCD-swizzled; bx<4 -> wh, else wt
__global__ __launch_bounds__(256) void ehet128(
    const u16* __restrict__ A, const u16* __restrict__ Bh, const u16* __restrict__ Bt,
    const float* __restrict__ bh_, const float* __restrict__ bt_,
    u16* __restrict__ Oh, u16* __restrict__ Ot)
{
    __shared__ __align__(16) u16 ldsbuf[3 * 8192];
    int bx, by;
    xcd_swz(blockIdx.y * 8 + blockIdx.x, bx, by);
    const int m0 = by * 128, n0 = (bx & 3) * 128;
    const u16* B = (bx < 4) ? Bh : Bt;
    const float* bias = (bx < 4) ? bh_ : bt_;
    u16* O = (bx < 4) ? Oh : Ot;
    f32x4 acc[4][4] = {};
    kloop128p<512>(A + (size_t)m0 * 512, B + (size_t)n0 * 512, ldsbuf, acc);
    epilogue128<0, 0>(acc, bias, nullptr, O, 512, m0, n0);
}

// ---------------------------------------------------------------------------
// R14 (best-measured): fused 128x256 logits K-loop. ONE kloop per block,
// 32 MFMA per barrier, counted vmcnt(6), 3 x 24KB buffers, depth-2 prefetch.
template<int KT>
__device__ __forceinline__ void kloop256w(const u16* __restrict__ Ag,
                                          const u16* __restrict__ Bg,
                                          u16* lds, f32x4 (&acc)[4][8]) {
    const int tid = threadIdx.x;
    const int wave = tid >> 6, lane = tid & 63;
    const int lr = lane & 15, quad = lane >> 4;
    const int wm = (wave & 1) * 64;
    const int r = tid >> 2;
    const int g8 = (((tid & 3) ^ ((tid >> 3) & 3))) * 8;   // swizzled k-block
    const int kbr8 = (quad ^ ((lr >> 1) & 3)) * 8;         // reader slot
    const u16* ga0 = Ag + (size_t)r * KT + g8;
    const u16* ga1 = ga0 + (size_t)64 * KT;
    const u16* gb0 = Bg + (size_t)r * KT + g8;
    const u16* gb1 = gb0 + (size_t)64 * KT;
    const u16* gb2 = gb0 + (size_t)128 * KT;
    const u16* gb3 = gb0 + (size_t)192 * KT;
    const int wofs = wave * 512;                           // wave-uniform chunk
    constexpr int NT = KT / 32;
    constexpr int BUF = 12288;   // u16 per buffer: A[0,4K) B0[4K,8K) B1[8K,12K)
    auto stage = [&](int t, int koff) {
        u16* b = lds + (t % 3) * BUF;
        gl_lds16(ga0 + koff, b + wofs);
        gl_lds16(ga1 + koff, b + wofs + 2048);
        gl_lds16(gb0 + koff, b + 4096 + wofs);
        gl_lds16(gb1 + koff, b + 4096 + wofs + 2048);
        gl_lds16(gb2 + koff, b + 8192 + wofs);
        gl_lds16(gb3 + koff, b + 8192 + wofs + 2048);
    };
    stage(0, 0);
    stage(1, 32);
    #pragma unroll
    for (int t = 0; t < NT; t++) {
        if (t + 1 < NT) asm volatile("s_waitcnt vmcnt(6)" ::: "memory");
        else            asm volatile("s_waitcnt vmcnt(0)" ::: "memory");
        __builtin_amdgcn_s_barrier();    // all waves' stage(t) landed
        if (t + 2 < NT) stage(t + 2, (t + 2) * 32);
        const u16* Ab = lds + (t % 3) * BUF;
        const u16* Bb = Ab + 4096 + (wave >> 1) * 4096;    // B0 or B1
        bh8 af[4];
        #pragma unroll
        for (int i = 0; i < 4; i++)
            af[i] = *(const bh8*)&Ab[(wm + i * 16 + lr) * 32 + kbr8];
        __builtin_amdgcn_s_setprio(1);   // T5
        #pragma unroll
        for (int g = 0; g < 2; g++) {    // two B-frag groups -> bounded VGPR
            bh8 bf_[4];
            #pragma unroll
            for (int j = 0; j < 4; j++)
                bf_[j] = *(const bh8*)&Bb[((g * 4 + j) * 16 + lr) * 32 + kbr8];
            #pragma unroll
            for (int mi = 0; mi < 4; mi++)
                #pragma unroll
                for (int j = 0; j < 4; j++)
                    acc[mi][g * 4 + j] = __builtin_amdgcn_mfma_f32_16x16x32_bf16(
                        af[mi], bf_[j], acc[mi][g * 4 + j], 0, 0, 0);
        }
        __builtin_amdgcn_s_setprio(0);
    }
    // caller must __syncthreads() before reusing LDS.
}

// fused logits GEMM + branchless packed top-6 (exact R14/R17 restore, 115us).
// Block = 128 rows x 256 cols, grid (32, 64), XCD-swizzled. LDS = 72KB
// (3x24KB staging; 33KB top-k scratch S aliases it) -> 2 blocks/CU.
__global__ __launch_bounds__(256, 2) void logits_topk(
    const u16* __restrict__ Ah, const u16* __restrict__ Bt, u32* __restrict__ tvp)
{
    __shared__ __align__(16) u16 ldsbuf[3 * 12288];   // 72KB
    u32* S = (u32*)ldsbuf;                            // 64*129*4 = 33KB alias
    const int tid = threadIdx.x;
    int bx, by;
    xcd_swz(blockIdx.y * 32 + blockIdx.x, bx, by);
    const int m0 = by * 128;
    const int cb0 = bx * 256;
    const int lane = tid & 63, wave = tid >> 6;
    const int wh = wave & 1;                     // row-half this wave owns
    const int wnh = wave >> 1;                   // col-half this wave owns
    const int lr = lane & 15, quad = lane >> 4;
    const int srow = tid >> 2, scg = tid & 3;    // scan: 64 rows x 4 col-groups

    f32x4 acc[4][8] = {};
    kloop256w<512>(Ah + (size_t)m0 * 512, Bt + (size_t)cb0 * 512, ldsbuf, acc);

    u32 v[2][6] = {{0,0,0,0,0,0},{0,0,0,0,0,0}};
    #pragma unroll
    for (int h = 0; h < 2; h++) {
        #pragma unroll
        for (int nh = 0; nh < 2; nh++) {
            __syncthreads();          // kloop / prior scan reads fully done
            if (wh == h && wnh == nh) {
                #pragma unroll
                for (int mi = 0; mi < 4; mi++)
                    #pragma unroll
                    for (int f = 0; f < 8; f++)
                        #pragma unroll
                        for (int i = 0; i < 4; i++) {
                            int colLocal = nh * 128 + f * 16 + lr;
                            S[(mi * 16 + quad * 4 + i) * 129 + f * 16 + lr]
                                = pack_vi(acc[mi][f][i], 255 - colLocal);
                        }
            }
            __syncthreads();
            // interleaved 8-elem chunks: bank = (srow + scg*8 + c)%32 -> 2-way
            const u32* Sr = &S[srow * 129 + scg * 8];
            #pragma unroll
            for (int ch = 0; ch < 4; ch++) {
                #pragma unroll
                for (int c = 0; c < 8; c++) {
                    u32 x = Sr[ch * 32 + c];
                    v[h][5] = max(v[h][5], min(v[h][4], x));
                    v[h][4] = max(v[h][4], min(v[h][3], x));
                    v[h][3] = max(v[h][3], min(v[h][2], x));
                    v[h][2] = max(v[h][2], min(v[h][1], x));
                    v[h][1] = max(v[h][1], min(v[h][0], x));
                    v[h][0] = max(v[h][0], x);
                }
            }
        }
    }
    // merge the four column-group lists per row through LDS, per row-half
    #pragma unroll
    for (int h = 0; h < 2; h++) {
        __syncthreads();
        {
            u32* dst = &S[srow * 129 + scg * 6];
            #pragma unroll
            for (int j = 0; j < 6; j++) dst[j] = v[h][j];
        }
        __syncthreads();
        if (tid < 64) {
            u32 m0v = 0, m1v = 0, m2v = 0, m3v = 0, m4v = 0, m5v = 0;
            const u32* Sr = &S[tid * 129];
            #pragma unroll
            for (int s = 0; s < 24; s++) {
                u32 x = Sr[s];
                m5v = max(m5v, min(m4v, x));
                m4v = max(m4v, min(m3v, x));
                m3v = max(m3v, min(m2v, x));
                m2v = max(m2v, min(m1v, x));
                m1v = max(m1v, min(m0v, x));
                m0v = max(m0v, x);
            }
            u32* dst = tvp + (size_t)(m0 + h * 64 + tid) * 192 + bx * 6;
            dst[0] = m0v; dst[1] = m1v; dst[2] = m2v;
            dst[3] = m3v; dst[4] = m4v; dst[5] = m5v;
        }
    }
}

// merge 32 packed partial top-6 lists per row -> final top-6 (fp32 val + idx)
__global__ void topk_merge(const u32* __restrict__ tvp,
                           float* __restrict__ tv, int* __restrict__ ti)
{
    int r = blockIdx.x * 64 + threadIdx.x;
    u32 v[6]; int ix[6];
    #pragma unroll
    for (int j = 0; j < 6; j++) { v[j] = 0; ix[j] = 0; }
    const u32* pv = tvp + (size_t)r * 192;
    for (int b = 0; b < 32; b++) {
        #pragma unroll
        for (int j2 = 0; j2 < 6; j2++) {
            u32 p = pv[b * 6 + j2];
            if (p <= v[5]) break;     // group is descending: rest can't insert
            v[5] = p; ix[5] = b * 256 + 255 - (int)(p & 255u);
            #pragma unroll
            for (int j = 5; j > 0; j--) {
                if (v[j] > v[j - 1]) {
                    u32 tf = v[j]; v[j] = v[j - 1]; v[j - 1] = tf;
                    int tx = ix[j]; ix[j] = ix[j - 1]; ix[j - 1] = tx;
                }
            }
        }
    }
    #pragma unroll
    for (int j = 0; j < 6; j++) {
        tv[(size_t)r * 6 + j] = unpack_v(v[j]) * SCALE_F;
        ti[(size_t)r * 6 + j] = ix[j];
    }
}

// ---------------------------------------------------------------------------
// neighbor aggregation, one WAVE per row (no block barriers). fp32 math.
__global__ __launch_bounds__(256) void neighbor_kernel(
    const u16* __restrict__ eH, const u16* __restrict__ eT,
    const float* __restrict__ tv, const int* __restrict__ ti,
    u16* __restrict__ s1, u16* __restrict__ s2)
{
    const int tid = threadIdx.x, wave = tid >> 6, lane = tid & 63;
    const int n = blockIdx.x * 4 + wave;
    float tw[6]; int id[6];
    #pragma unroll
    for (int j = 0; j < 6; j++) {
        tw[j] = tv[n * 6 + j];
        int t = ti[n * 6 + j];
        id[j] = ((unsigned)t < 8192u) ? t : 0;
    }
    float mx = tw[0];
    #pragma unroll
    for (int j = 1; j < 6; j++) mx = fmaxf(mx, tw[j]);
    float p[6]; float ps = 0.f;
    #pragma unroll
    for (int j = 0; j < 6; j++) { p[j] = __expf(tw[j] - mx); ps += p[j]; }
    float inv = 1.0f / ps;
    #pragma unroll
    for (int j = 0; j < 6; j++) p[j] *= inv;

    const size_t base = (size_t)n * 512 + lane * 8;
    float eh[8];
    { bh8 v = *(const bh8*)(eH + base);
      #pragma unroll
      for (int c = 0; c < 8; c++) eh[c] = (float)v[c]; }
    float nb[6][8];
    #pragma unroll
    for (int j = 0; j < 6; j++) {
        bh8 v = *(const bh8*)(eT + (size_t)id[j] * 512 + lane * 8);
        #pragma unroll
        for (int c = 0; c < 8; c++) nb[j][c] = (float)v[c];
    }
    float ka[6];
    #pragma unroll
    for (int j = 0; j < 6; j++) {
        float s = 0.f;
        #pragma unroll
        for (int c = 0; c < 8; c++) {
            float e = p[j] * nb[j][c] + (1.f - p[j]) * eh[c];
            float x = eh[c] + e;
            x = fminf(fmaxf(x, -15.f), 15.f);
            float ex = __expf(2.f * x);
            float g = 1.f - 2.f / (ex + 1.f);   // tanh
            s += nb[j][c] * g;
        }
        #pragma unroll
        for (int off = 32; off > 0; off >>= 1) s += __shfl_down(s, off);
        ka[j] = __shfl(s, 0);
    }
    float m2 = ka[0];
    #pragma unroll
    for (int j = 1; j < 6; j++) m2 = fmaxf(m2, ka[j]);
    float kp[6]; float ks = 0.f;
    #pragma unroll
    for (int j = 0; j < 6; j++) { kp[j] = __expf(ka[j] - m2); ks += kp[j]; }
    float inv2 = 1.0f / ks;
    #pragma unroll
    for (int j = 0; j < 6; j++) kp[j] *= inv2;
    bh8 o1, o2;
    #pragma unroll
    for (int c = 0; c < 8; c++) {
        float eN = 0.f;
        #pragma unroll
        for (int j = 0; j < 6; j++) eN += kp[j] * nb[j][c];
        o1[c] = (bh)(eh[c] + eN);
        o2[c] = (bh)(eh[c] * eN);
    }
    *(bh8*)(s1 + base) = o1;
    *(bh8*)(s2 + base) = o2;
}

// ---------------------------------------------------------------------------
__global__ void colsum_kernel(const u16* __restrict__ h, float* __restrict__ colsum) {
    int tid = threadIdx.x;
    int n0 = blockIdx.x * 32;
    float a0 = 0.f, a1 = 0.f;
    for (int k = 0; k < 32; k++) {
        size_t b = (size_t)(n0 + k) * 512;
        a0 += bf2f(h[b + tid]); a1 += bf2f(h[b + tid + 256]);
    }
    atomicAdd(&colsum[tid], a0);
    atomicAdd(&colsum[tid + 256], a1);
}

__global__ void meanmix_kernel(u16* __restrict__ h, const float* __restrict__ colsum) {
    size_t i = ((size_t)blockIdx.x * 256 + threadIdx.x) * 8;
    int col = (int)(i & 511);
    union { int4 v; u16 s[8]; } u;
    u.v = *(const int4*)&h[i];
    #pragma unroll
    for (int j = 0; j < 8; j++)
        u.s[j] = f2bf((bf2f(u.s[j]) + colsum[col + j] * (1.0f / 8192.0f)) * 0.5f);
    *(int4*)&h[i] = u.v;
}

__global__ __launch_bounds__(256) void att2_kernel(
    const float* __restrict__ a1, const float* __restrict__ w,
    const float* __restrict__ b, float* __restrict__ att)
{
    int row = blockIdx.x * 4 + (threadIdx.x >> 6);
    int lane = threadIdx.x & 63;
    const float* pr = a1 + (size_t)row * 256;
    float s = 0.f;
    #pragma unroll
    for (int k = 0; k < 4; k++) { int c = lane + k * 64; s += pr[c] * w[c]; }
    #pragma unroll
    for (int off = 32; off > 0; off >>= 1) s += __shfl_down(s, off);
    if (lane == 0) att[row] = s + b[0];
}

// parallel softmax stats: ordered-u32 atomicMax, then atomicAdd of exp sums
__global__ void att_max(const float* __restrict__ att, u32* __restrict__ scal_u) {
    int i = blockIdx.x * 256 + threadIdx.x;
    int lane = threadIdx.x & 63;
    u32 o = ordf(att[i]);
    #pragma unroll
    for (int off = 32; off > 0; off >>= 1) o = max(o, (u32)__shfl_down((int)o, off));
    if (lane == 0) atomicMax(&scal_u[0], o);
}
__global__ void att_sum(const float* __restrict__ att, float* __restrict__ scal) {
    int i = blockIdx.x * 256 + threadIdx.x;
    int lane = threadIdx.x & 63;
    float mx = unordf(((const u32*)scal)[0]);
    float e = __expf(att[i] - mx);
    #pragma unroll
    for (int off = 32; off > 0; off >>= 1) e += __shfl_down(e, off);
    if (lane == 0) atomicAdd(&scal[1], e);
}

__global__ void pooled_kernel(const u16* __restrict__ emb, const float* __restrict__ att,
                              const float* __restrict__ scal, float* __restrict__ pooled) {
    int tid = threadIdx.x;
    int n0 = blockIdx.x * 32;
    float mx = unordf(((const u32*)scal)[0]);
    float inv = 1.0f / scal[1];
    float a0 = 0.f, a1 = 0.f;
    for (int k = 0; k < 32; k++) {
        int n = n0 + k;
        float w = __expf(att[n] - mx) * inv;
        size_t b = (size_t)n * 512;
        a0 += w * bf2f(emb[b + tid]);
        a1 += w * bf2f(emb[b + tid + 256]);
    }
    atomicAdd(&pooled[tid], a0);
    atomicAdd(&pooled[tid + 256], a1);
}

__global__ void final_kernel(const float* __restrict__ pooled,
                             const float* __restrict__ g, const float* __restrict__ bln,
                             const float* __restrict__ fcw, const float* __restrict__ fcb,
                             float* __restrict__ out) {
    __shared__ float red[256];
    int tid = threadIdx.x;
    float x0 = pooled[tid], x1 = pooled[tid + 256];
    red[tid] = x0 + x1; __syncthreads();
    for (int s = 128; s > 0; s >>= 1) { if (tid < s) red[tid] += red[tid + s]; __syncthreads(); }
    float mu = red[0] * (1.0f / 512.0f); __syncthreads();
    float d0 = x0 - mu, d1 = x1 - mu;
    red[tid] = d0 * d0 + d1 * d1; __syncthreads();
    for (int s = 128; s > 0; s >>= 1) { if (tid < s) red[tid] += red[tid + s]; __syncthreads(); }
    float var = red[0] * (1.0f / 512.0f); __syncthreads();
    float rstd = rsqrtf(var + 1e-5f);
    float l0 = d0 * rstd * g[tid]       + bln[tid];
    float l1 = d1 * rstd * g[tid + 256] + bln[tid + 256];
    red[tid] = l0 * fcw[tid * 2] + l1 * fcw[(tid + 256) * 2]; __syncthreads();
    for (int s = 128; s > 0; s >>= 1) { if (tid < s) red[tid] += red[tid + s]; __syncthreads(); }
    float o0 = red[0] + fcb[0]; __syncthreads();
    red[tid] = l0 * fcw[tid * 2 + 1] + l1 * fcw[(tid + 256) * 2 + 1]; __syncthreads();
    for (int s = 128; s > 0; s >>= 1) { if (tid < s) red[tid] += red[tid + s]; __syncthreads(); }
    float o1 = red[0] + fcb[1];
    if (tid == 0) {
        float m = fmaxf(o0, o1);
        float e0 = expf(o0 - m), e1 = expf(o1 - m);
        float se = e0 + e1;
        out[0] = o0;
        out[1] = o1;
        out[2] = e0 / se;
        out[3] = e1 / se;
        out[4] = (o0 >= o1) ? 0.0f : 1.0f;
    }
}

// ---------------------------------------------------------------------------
extern "C" void kernel_launch(void* const* d_in, const int* in_sizes, int n_in,
                              void* d_out, int out_size, void* d_ws, size_t ws_size,
                              hipStream_t stream)
{
    const float* x      = (const float*)d_in[0];
    const float* fc1_w  = (const float*)d_in[1];
    const float* fc1_b  = (const float*)d_in[2];
    const float* wh_w   = (const float*)d_in[3];
    const float* wh_b   = (const float*)d_in[4];
    const float* wt_w   = (const float*)d_in[5];
    const float* wt_b   = (const float*)d_in[6];
    const float* lin1_w = (const float*)d_in[7];
    const float* lin1_b = (const float*)d_in[8];
    const float* lin2_w = (const float*)d_in[9];
    const float* lin2_b = (const float*)d_in[10];
    const float* att1_w = (const float*)d_in[11];
    const float* att1_b = (const float*)d_in[12];
    const float* att2_w = (const float*)d_in[13];
    const float* att2_b = (const float*)d_in[14];
    const float* ln_g   = (const float*)d_in[15];
    const float* ln_b   = (const float*)d_in[16];
    const float* fc_w   = (const float*)d_in[17];
    const float* fc_b   = (const float*)d_in[18];
    float* out = (float*)d_out;
    char* ws = (char*)d_ws;

    u16*   fc1T   = (u16*)(ws + 0);
    u16*   whT    = (u16*)(ws + 1048576);
    u16*   wtT    = (u16*)(ws + 1572864);
    u16*   l1T    = (u16*)(ws + 2097152);
    u16*   l2T    = (u16*)(ws + 2621440);
    u16*   a1T    = (u16*)(ws + 3145728);
    float* tv     = (float*)(ws + 3407872);
    int*   ti     = (int*)(ws + 3604480);
    float* att    = (float*)(ws + 3801088);
    float* colsum = (float*)(ws + 3833856);
    float* pooled = (float*)(ws + 3835904);
    float* scal   = (float*)(ws + 3837952);
    u32*   tvp    = (u32*)(ws + 4194304);
    u16*   hbf    = (u16*)(ws + 14680064);   // 8 MB  [h; later s1]
    u16*   ehbf   = (u16*)(ws + 23068672);   // 8 MB  [e_h; later a1 fp32]
    u16*   etbf   = (u16*)(ws + 31457280);   // 8 MB  [e_t; later emb]
    u16*   s2bf   = (u16*)(ws + 39845888);   // 8 MB  [s2]
    u16*   xbf    = (u16*)(ws + 23068672);   // 16 MB (x bf16; dead after fc1)
    float* a1f    = (float*)(ws + 23068672); // 8 MB fp32 (after e_h dead)

    transpose_cvt<<<5760, dim3(32, 8), 0, stream>>>(
        fc1_w, fc1T, wh_w, whT, wt_w, wtT, lin1_w, l1T, lin2_w, l2T, att1_w, a1T, x, xbf);
    hipMemsetAsync(colsum, 0, 4160, stream);   // colsum + pooled + scal

    gemm64x128<1, 0, 1024, 4><<<dim3(4, 128), 256, 0, stream>>>(xbf, fc1T, fc1_b, nullptr, hbf, 512);
    colsum_kernel<<<256, 256, 0, stream>>>(hbf, colsum);
    meanmix_kernel<<<2048, 256, 0, stream>>>(hbf, colsum);

    ehet128<<<dim3(8, 64), 256, 0, stream>>>(hbf, whT, wtT, wh_b, wt_b, ehbf, etbf);

    logits_topk<<<dim3(32, 64), 256, 0, stream>>>(ehbf, etbf, tvp);
    topk_merge<<<128, 64, 0, stream>>>(tvp, tv, ti);

    neighbor_kernel<<<2048, 256, 0, stream>>>(ehbf, etbf, tv, ti, hbf, s2bf);

    lin12_64x128<<<dim3(4, 128), 256, 0, stream>>>(hbf, l1T, lin1_b, s2bf, l2T, lin2_b, etbf);

    gemm64<2, 1, 512><<<dim3(4, 128), 256, 0, stream>>>(etbf, a1T, att1_b, a1f, nullptr, 256);
    att2_kernel<<<2048, 256, 0, stream>>>(a1f, att2_w, att2_b, att);
    att_max<<<32, 256, 0, stream>>>(att, (u32*)scal);
    att_sum<<<32, 256, 0, stream>>>(att, scal);
    pooled_kernel<<<256, 256, 0, stream>>>(etbf, att, scal, pooled);

    final_kernel<<<1, 256, 0, stream>>>(pooled, ln_g, ln_b, fc_w, fc_b, out);
}

// Round 10
// 338.729 us; speedup vs baseline: 1.0425x; 1.0231x over previous
//
#include <hip/hip_runtime.h>
#include <hip/hip_bf16.h>
#include <cstdint>
#include <math.h>

typedef unsigned short u16;
typedef unsigned int u32;
typedef __bf16 bh;
typedef bh bh8 __attribute__((ext_vector_type(8)));
typedef float f32x4 __attribute__((ext_vector_type(4)));

#define SCALE_F 0.04419417382415922f  // 512^-0.5

__device__ __forceinline__ float bf2f(u16 u) {
    union { float f; unsigned int i; } v; v.i = ((unsigned int)u) << 16; return v.f;
}
__device__ __forceinline__ u16 f2bf(float f) {
    __hip_bfloat16 h = __float2bfloat16(f);
    return __builtin_bit_cast(u16, h);
}
__device__ __forceinline__ bh8 ld8_f32(const float* p) {
    float4 f0 = *(const float4*)p;
    float4 f1 = *(const float4*)(p + 4);
    bh8 r;
    r[0] = (bh)f0.x; r[1] = (bh)f0.y; r[2] = (bh)f0.z; r[3] = (bh)f0.w;
    r[4] = (bh)f1.x; r[5] = (bh)f1.y; r[6] = (bh)f1.z; r[7] = (bh)f1.w;
    return r;
}

// ordered-uint transforms (monotone with float order)
__device__ __forceinline__ u32 ordf(float f) {
    u32 u = __float_as_uint(f);
    return u ^ ((u32)((int)u >> 31) | 0x80000000u);
}
__device__ __forceinline__ float unordf(u32 s) {
    u32 u = (s & 0x80000000u) ? (s ^ 0x80000000u) : ~s;
    return __uint_as_float(u);
}
// 24-bit ordered value | 8-bit inverted local col idx (tie -> smaller idx wins)
__device__ __forceinline__ u32 pack_vi(float v, int inv_idx) {
    return (ordf(v) & 0xFFFFFF00u) | (u32)inv_idx;
}
__device__ __forceinline__ float unpack_v(u32 p) {
    return unordf(p & 0xFFFFFF00u);
}

// direct global->LDS 16B per lane; lds base wave-uniform (dest = base + lane*16)
__device__ __forceinline__ void gl_lds16(const u16* g, u16* l) {
    __builtin_amdgcn_global_load_lds(
        (const __attribute__((address_space(1))) void*)g,
        (__attribute__((address_space(3))) void*)l, 16, 0, 0);
}

// bijective XCD swizzle (T1): grids with NY=64 -> each XCD owns a contiguous
// 8-row y-range, y-inner order so consecutive blocks share B panels in L2.
__device__ __forceinline__ void xcd_swz(int bid, int& x, int& y) {
    int xcd = bid & 7, idx = bid >> 3;
    x = idx >> 3;
    y = xcd * 8 + (idx & 7);
}

// ---------------------------------------------------------------------------
// 6 weight transposes (fp32 [R,C] -> bf16 [C,R]) + x fp32->bf16, one dispatch
__global__ void transpose_cvt(const float* s0, u16* d0, const float* s1, u16* d1,
                              const float* s2, u16* d2, const float* s3, u16* d3,
                              const float* s4, u16* d4, const float* s5, u16* d5,
                              const float* xs, u16* xd) {
    int b = blockIdx.x;
    if (b >= 1664) {  // cvt_x part: 4096 blocks, 8 elems/thread
        int t = threadIdx.y * 32 + threadIdx.x;
        size_t i = ((size_t)(b - 1664) * 256 + t) * 8;
        *(bh8*)(xd + i) = ld8_f32(xs + i);
        return;
    }
    __shared__ float tsh[32][33];
    const float* src; u16* dst; int R, C, tt;
    if      (b < 512)  { src = s0; dst = d0; R = 1024; C = 512; tt = b; }
    else if (b < 768)  { src = s1; dst = d1; R = 512;  C = 512; tt = b - 512; }
    else if (b < 1024) { src = s2; dst = d2; R = 512;  C = 512; tt = b - 768; }
    else if (b < 1280) { src = s3; dst = d3; R = 512;  C = 512; tt = b - 1024; }
    else if (b < 1536) { src = s4; dst = d4; R = 512;  C = 512; tt = b - 1280; }
    else               { src = s5; dst = d5; R = 512;  C = 256; tt = b - 1536; }
    int ntx = C >> 5;
    int bx = (tt % ntx) * 32, by = (tt / ntx) * 32;
    int x = threadIdx.x, y = threadIdx.y;
    for (int i = 0; i < 32; i += 8)
        tsh[y + i][x] = src[(size_t)(by + y + i) * C + bx + x];
    __syncthreads();
    for (int i = 0; i < 32; i += 8)
        dst[(size_t)(bx + y + i) * R + by + x] = f2bf(tsh[x][y + i]);
}

// ---------------------------------------------------------------------------
// R10-proven 64-row K-loop (single buffer, 2 barriers/iter). High residency
// hides the drain via cross-block TLP. Used by att12_fused.
template<int KT, int NF>
__device__ __forceinline__ void kloop64(const u16* __restrict__ Ag, const u16* __restrict__ Bg,
                                        u16* Alds, u16* Blds, f32x4 (&acc)[2][NF]) {
    const int tid = threadIdx.x;
    const int wave = tid >> 6, lane = tid & 63;
    const int lr = lane & 15, quad = lane >> 4;
    const int wm = (wave & 1) * 32, wn = (wave >> 1) * (NF * 16);
    const int r = tid >> 2;
    const int g8 = (((tid & 3) ^ ((tid >> 3) & 3))) * 8;   // swizzled k-block
    const int kbr8 = (quad ^ ((lr >> 1) & 3)) * 8;         // reader slot
    const u16* ga  = Ag + (size_t)r * KT + g8;
    const u16* gb0 = Bg + (size_t)r * KT + g8;
    const u16* gb1 = gb0 + (size_t)64 * KT;                // B rows 64..127 (NF=4)
    u16* la = Alds + wave * 512;   // wave-uniform
    u16* lb = Blds + wave * 512;
    #pragma unroll
    for (int k0 = 0; k0 < KT; k0 += 32) {
        __syncthreads();                 // prior reads done before LDS overwrite
        gl_lds16(ga + k0, la);
        gl_lds16(gb0 + k0, lb);
        if (NF == 4) gl_lds16(gb1 + k0, lb + 2048);
        __syncthreads();                 // drains vmcnt -> LDS writes visible
        bh8 af[2], bf_[NF];
        #pragma unroll
        for (int i = 0; i < 2; i++)
            af[i] = *(const bh8*)&Alds[(wm + i * 16 + lr) * 32 + kbr8];
        #pragma unroll
        for (int i = 0; i < NF; i++)
            bf_[i] = *(const bh8*)&Blds[(wn + i * 16 + lr) * 32 + kbr8];
        #pragma unroll
        for (int mi = 0; mi < 2; mi++)
            #pragma unroll
            for (int ni = 0; ni < NF; ni++)
                acc[mi][ni] = __builtin_amdgcn_mfma_f32_16x16x32_bf16(
                    af[mi], bf_[ni], acc[mi][ni], 0, 0, 0);
    }
}

// ---------------------------------------------------------------------------
// R20: fused att1+att2. att[row] = sum_col lrelu(emb@W1+b1)[row][col]*w2[col].
// att2's bias is DROPPED: softmax over rows is invariant to a constant shift,
// and att itself is not an output. Removes the 8MB a1f intermediate (16MB of
// HBM round-trip) and one launch. kloop64 grid (4,128) = 512 blocks. Per
// thread: 2 cols x 8 rows; per-row dot partial over its 2 cols; shfl_down
// reduce across the 16-lane lr group; lr==0 atomicAdds 8 row-partials
// (8 atomics/row total across the grid -> negligible contention).
__global__ __launch_bounds__(256) void att12_fused(
    const u16* __restrict__ A, const u16* __restrict__ B,
    const float* __restrict__ b1, const float* __restrict__ w2,
    float* __restrict__ att)
{
    __shared__ __align__(16) u16 Alds[64 * 32];
    __shared__ __align__(16) u16 Blds[64 * 32];
    const int m0 = blockIdx.y * 64, n0 = blockIdx.x * 64;
    f32x4 acc[2][2] = {};
    kloop64<512, 2>(A + (size_t)m0 * 512, B + (size_t)n0 * 512, Alds, Blds, acc);
    const int tid = threadIdx.x;
    const int wave = tid >> 6, lane = tid & 63;
    const int lr = lane & 15, quad = lane >> 4;
    const int wm = (wave & 1) * 32, wn = (wave >> 1) * 32;
    float w0  = w2[n0 + wn + lr],      w1  = w2[n0 + wn + 16 + lr];
    float bs0 = b1[n0 + wn + lr],      bs1 = b1[n0 + wn + 16 + lr];
    #pragma unroll
    for (int mi = 0; mi < 2; mi++) {
        #pragma unroll
        for (int i = 0; i < 4; i++) {
            float v0 = acc[mi][0][i] + bs0;
            v0 = (v0 > 0.0f) ? v0 : 0.01f * v0;
            float v1 = acc[mi][1][i] + bs1;
            v1 = (v1 > 0.0f) ? v1 : 0.01f * v1;
            float s = v0 * w0 + v1 * w1;
            s += __shfl_down(s, 8);
            s += __shfl_down(s, 4);
            s += __shfl_down(s, 2);
            s += __shfl_down(s, 1);
            if (lr == 0)
                atomicAdd(&att[m0 + wm + mi * 16 + quad * 4 + i], s);
        }
    }
}

// ---------------------------------------------------------------------------
// 128x128-tile K-loop with counted-vmcnt pipeline (T4): 3 LDS buffers,
// prefetch depth 2, one raw s_barrier per K-step, s_waitcnt vmcnt(4).
template<int KT>
__device__ __forceinline__ void kloop128p(const u16* __restrict__ Ag,
                                          const u16* __restrict__ Bg,
                                          u16* lds, f32x4 (&acc)[4][4]) {
    const int tid = threadIdx.x;
    const int wave = tid >> 6, lane = tid & 63;
    const int lr = lane & 15, quad = lane >> 4;
    const int wm = (wave & 1) * 64, wn = (wave >> 1) * 64;
    const int r = tid >> 2;
    const int g8 = (((tid & 3) ^ ((tid >> 3) & 3))) * 8;   // swizzled k-block
    const int kbr8 = (quad ^ ((lr >> 1) & 3)) * 8;         // reader slot
    const u16* ga0 = Ag + (size_t)r * KT + g8;
    const u16* ga1 = ga0 + (size_t)64 * KT;                // A rows 64..127
    const u16* gb0 = Bg + (size_t)r * KT + g8;
    const u16* gb1 = gb0 + (size_t)64 * KT;                // B rows 64..127
    const int wofs = wave * 512;                           // wave-uniform chunk
    constexpr int NT = KT / 32;
    gl_lds16(ga0,      lds + wofs);
    gl_lds16(ga1,      lds + wofs + 2048);
    gl_lds16(gb0,      lds + 4096 + wofs);
    gl_lds16(gb1,      lds + 4096 + wofs + 2048);
    gl_lds16(ga0 + 32, lds + 8192 + wofs);
    gl_lds16(ga1 + 32, lds + 8192 + wofs + 2048);
    gl_lds16(gb0 + 32, lds + 8192 + 4096 + wofs);
    gl_lds16(gb1 + 32, lds + 8192 + 4096 + wofs + 2048);
    #pragma unroll
    for (int t = 0; t < NT; t++) {
        if (t + 1 < NT) asm volatile("s_waitcnt vmcnt(4)" ::: "memory");
        else            asm volatile("s_waitcnt vmcnt(0)" ::: "memory");
        __builtin_amdgcn_s_barrier();    // all waves' stage(t) landed
        if (t + 2 < NT) {
            const int k2 = (t + 2) * 32;
            u16* b = lds + ((t + 2) % 3) * 8192;
            gl_lds16(ga0 + k2, b + wofs);
            gl_lds16(ga1 + k2, b + wofs + 2048);
            gl_lds16(gb0 + k2, b + 4096 + wofs);
            gl_lds16(gb1 + k2, b + 4096 + wofs + 2048);
        }
        const u16* Ab = lds + (t % 3) * 8192;
        const u16* Bb = Ab + 4096;
        bh8 af[4], bf_[4];
        #pragma unroll
        for (int i = 0; i < 4; i++) {
            af[i]  = *(const bh8*)&Ab[(wm + i * 16 + lr) * 32 + kbr8];
            bf_[i] = *(const bh8*)&Bb[(wn + i * 16 + lr) * 32 + kbr8];
        }
        __builtin_amdgcn_s_setprio(1);   // T5
        #pragma unroll
        for (int mi = 0; mi < 4; mi++)
            #pragma unroll
            for (int ni = 0; ni < 4; ni++)
                acc[mi][ni] = __builtin_amdgcn_mfma_f32_16x16x32_bf16(
                    af[mi], bf_[ni], acc[mi][ni], 0, 0, 0);
        __builtin_amdgcn_s_setprio(0);
    }
    // caller must __syncthreads() before reusing LDS.
}

template<int ACT, int F32OUT>
__device__ __forceinline__ void epilogue128(f32x4 (&acc)[4][4], const float* bias,
                                            float* Cf, u16* Cb, int N, int m0, int n0) {
    const int tid = threadIdx.x;
    const int wave = tid >> 6, lane = tid & 63;
    const int lr = lane & 15, quad = lane >> 4;
    const int wm = (wave & 1) * 64, wn = (wave >> 1) * 64;
    #pragma unroll
    for (int ni = 0; ni < 4; ni++) {
        int col = n0 + wn + ni * 16 + lr;
        float bs = bias[col];
        #pragma unroll
        for (int mi = 0; mi < 4; mi++) {
            #pragma unroll
            for (int i = 0; i < 4; i++) {
                int row = m0 + wm + mi * 16 + quad * 4 + i;
                float v = acc[mi][ni][i] + bs;
                if (ACT == 1) v = fmaxf(v, 0.0f);
                if (ACT == 2) v = (v > 0.0f) ? v : 0.01f * v;
                size_t o = (size_t)row * N + col;
                if (F32OUT) Cf[o] = v;
                else        Cb[o] = f2bf(v);
            }
        }
    }
}

// 128x128-tile GEMM, XCD-swizzled grid (GNX, 64). Used for fc1 (GNX=4).
template<int ACT, int F32OUT, int KT, int GNX>
__global__ __launch_bounds__(256) void gemm128(
    const u16* __restrict__ A, const u16* __restrict__ B, const float* __restrict__ bias,
    float* __restrict__ Cf, u16* __restrict__ Cb, int N)
{
    __shared__ __align__(16) u16 ldsbuf[3 * 8192];
    int bx, by;
    xcd_swz(blockIdx.y * GNX + blockIdx.x, bx, by);
    const int m0 = by * 128, n0 = bx * 128;
    f32x4 acc[4][4] = {};
    kloop128p<KT>(A + (size_t)m0 * KT, B + (size_t)n0 * KT, ldsbuf, acc);
    epilogue128<ACT, F32OUT>(acc, bias, Cf, Cb, N, m0, n0);
}

// fused e_h / e_t on 128-tiles: grid (8, 64) XCD-swizzled; bx<4 -> wh, else wt
__global__ __launch_bounds__(256) void ehet128(
    const u16* __restrict__ A, const u16* __restrict__ Bh, const u16* __restrict__ Bt,
    const float* __restrict__ bh_, const float* __restrict__ bt_,
    u16* __restrict__ Oh, u16* __restrict__ Ot)
{
    __shared__ __align__(16) u16 ldsbuf[3 * 8192];
    int bx, by;
    xcd_swz(blockIdx.y * 8 + blockIdx.x, bx, by);
    const int m0 = by * 128, n0 = (bx & 3) * 128;
    const u16* B = (bx < 4) ? Bh : Bt;
    const float* bias = (bx < 4) ? bh_ : bt_;
    u16* O = (bx < 4) ? Oh : Ot;
    f32x4 acc[4][4] = {};
    kloop128p<512>(A + (size_t)m0 * 512, B + (size_t)n0 * 512, ldsbuf, acc);
    epilogue128<0, 0>(acc, bias, nullptr, O, 512, m0, n0);
}

// ---------------------------------------------------------------------------
// R17: fused emb = lrelu(s1@l1+b1) + lrelu(s2@l2+b2) on 128-tiles: two
// sequential counted-vmcnt kloops sharing the staging LDS.
__global__ __launch_bounds__(256) void lin12_128(
    const u16* __restrict__ A1, const u16* __restrict__ B1, const float* __restrict__ b1,
    const u16* __restrict__ A2, const u16* __restrict__ B2, const float* __restrict__ b2,
    u16* __restrict__ O)
{
    __shared__ __align__(16) u16 ldsbuf[3 * 8192];
    int bx, by;
    xcd_swz(blockIdx.y * 4 + blockIdx.x, bx, by);
    const int m0 = by * 128, n0 = bx * 128;
    f32x4 acc1[4][4] = {}, acc2[4][4] = {};
    kloop128p<512>(A1 + (size_t)m0 * 512, B1 + (size_t)n0 * 512, ldsbuf, acc1);
    __syncthreads();   // kloop1 reads done before kloop2 prologue restages buf0
    kloop128p<512>(A2 + (size_t)m0 * 512, B2 + (size_t)n0 * 512, ldsbuf, acc2);
    const int tid = threadIdx.x;
    const int wave = tid >> 6, lane = tid & 63;
    const int lr = lane & 15, quad = lane >> 4;
    const int wm = (wave & 1) * 64, wn = (wave >> 1) * 64;
    #pragma unroll
    for (int ni = 0; ni < 4; ni++) {
        int col = n0 + wn + ni * 16 + lr;
        float bs1 = b1[col], bs2 = b2[col];
        #pragma unroll
        for (int mi = 0; mi < 4; mi++) {
            #pragma unroll
            for (int i = 0; i < 4; i++) {
                int row = m0 + wm + mi * 16 + quad * 4 + i;
                float v1 = acc1[mi][ni][i] + bs1;
                v1 = (v1 > 0.0f) ? v1 : 0.01f * v1;
                float v2 = acc2[mi][ni][i] + bs2;
                v2 = (v2 > 0.0f) ? v2 : 0.01f * v2;
                O[(size_t)row * 512 + col] = f2bf(v1 + v2);
            }
        }
    }
}

// ---------------------------------------------------------------------------
// R14 (best-measured): fused 128x256 logits K-loop. ONE kloop per block,
// 32 MFMA per barrier, counted vmcnt(6), 3 x 24KB buffers, depth-2 prefetch.
template<int KT>
__device__ __forceinline__ void kloop256w(const u16* __restrict__ Ag,
                                          const u16* __restrict__ Bg,
                                          u16* lds, f32x4 (&acc)[4][8]) {
    const int tid = threadIdx.x;
    const int wave = tid >> 6, lane = tid & 63;
    const int lr = lane & 15, quad = lane >> 4;
    const int wm = (wave & 1) * 64;
    const int r = tid >> 2;
    const int g8 = (((tid & 3) ^ ((tid >> 3) & 3))) * 8;   // swizzled k-block
    const int kbr8 = (quad ^ ((lr >> 1) & 3)) * 8;         // reader slot
    const u16* ga0 = Ag + (size_t)r * KT + g8;
    const u16* ga1 = ga0 + (size_t)64 * KT;
    const u16* gb0 = Bg + (size_t)r * KT + g8;
    const u16* gb1 = gb0 + (size_t)64 * KT;
    const u16* gb2 = gb0 + (size_t)128 * KT;
    const u16* gb3 = gb0 + (size_t)192 * KT;
    const int wofs = wave * 512;                           // wave-uniform chunk
    constexpr int NT = KT / 32;
    constexpr int BUF = 12288;   // u16 per buffer: A[0,4K) B0[4K,8K) B1[8K,12K)
    auto stage = [&](int t, int koff) {
        u16* b = lds + (t % 3) * BUF;
        gl_lds16(ga0 + koff, b + wofs);
        gl_lds16(ga1 + koff, b + wofs + 2048);
        gl_lds16(gb0 + koff, b + 4096 + wofs);
        gl_lds16(gb1 + koff, b + 4096 + wofs + 2048);
        gl_lds16(gb2 + koff, b + 8192 + wofs);
        gl_lds16(gb3 + koff, b + 8192 + wofs + 2048);
    };
    stage(0, 0);
    stage(1, 32);
    #pragma unroll
    for (int t = 0; t < NT; t++) {
        if (t + 1 < NT) asm volatile("s_waitcnt vmcnt(6)" ::: "memory");
        else            asm volatile("s_waitcnt vmcnt(0)" ::: "memory");
        __builtin_amdgcn_s_barrier();    // all waves' stage(t) landed
        if (t + 2 < NT) stage(t + 2, (t + 2) * 32);
        const u16* Ab = lds + (t % 3) * BUF;
        const u16* Bb = Ab + 4096 + (wave >> 1) * 4096;    // B0 or B1
        bh8 af[4];
        #pragma unroll
        for (int i = 0; i < 4; i++)
            af[i] = *(const bh8*)&Ab[(wm + i * 16 + lr) * 32 + kbr8];
        __builtin_amdgcn_s_setprio(1);   // T5
        #pragma unroll
        for (int g = 0; g < 2; g++) {    // two B-frag groups -> bounded VGPR
            bh8 bf_[4];
            #pragma unroll
            for (int j = 0; j < 4; j++)
                bf_[j] = *(const bh8*)&Bb[((g * 4 + j) * 16 + lr) * 32 + kbr8];
            #pragma unroll
            for (int mi = 0; mi < 4; mi++)
                #pragma unroll
                for (int j = 0; j < 4; j++)
                    acc[mi][g * 4 + j] = __builtin_amdgcn_mfma_f32_16x16x32_bf16(
                        af[mi], bf_[j], acc[mi][g * 4 + j], 0, 0, 0);
        }
        __builtin_amdgcn_s_setprio(0);
    }
    // caller must __syncthreads() before reusing LDS.
}

// fused logits GEMM + branchless packed top-6 (exact R14/R17 form, 115us).
// Block = 128 rows x 256 cols, grid (32, 64), XCD-swizzled. LDS = 72KB
// (3x24KB staging; 33KB top-k scratch S aliases it) -> 2 blocks/CU.
__global__ __launch_bounds__(256, 2) void logits_topk(
    const u16* __restrict__ Ah, const u16* __restrict__ Bt, u32* __restrict__ tvp)
{
    __shared__ __align__(16) u16 ldsbuf[3 * 12288];   // 72KB
    u32* S = (u32*)ldsbuf;                            // 64*129*4 = 33KB alias
    const int tid = threadIdx.x;
    int bx, by;
    xcd_swz(blockIdx.y * 32 + blockIdx.x, bx, by);
    const int m0 = by * 128;
    const int cb0 = bx * 256;
    const int lane = tid & 63, wave = tid >> 6;
    const int wh = wave & 1;                     // row-half this wave owns
    const int wnh = wave >> 1;                   // col-half this wave owns
    const int lr = lane & 15, quad = lane >> 4;
    const int srow = tid >> 2, scg = tid & 3;    // scan: 64 rows x 4 col-groups

    f32x4 acc[4][8] = {};
    kloop256w<512>(Ah + (size_t)m0 * 512, Bt + (size_t)cb0 * 512, ldsbuf, acc);

    u32 v[2][6] = {{0,0,0,0,0,0},{0,0,0,0,0,0}};
    #pragma unroll
    for (int h = 0; h < 2; h++) {
        #pragma unroll
        for (int nh = 0; nh < 2; nh++) {
            __syncthreads();          // kloop / prior scan reads fully done
            if (wh == h && wnh == nh) {
                #pragma unroll
                for (int mi = 0; mi < 4; mi++)
                    #pragma unroll
                    for (int f = 0; f < 8; f++)
                        #pragma unroll
                        for (int i = 0; i < 4; i++) {
                            int colLocal = nh * 128 + f * 16 + lr;
                            S[(mi * 16 + quad * 4 + i) * 129 + f * 16 + lr]
                                = pack_vi(acc[mi][f][i], 255 - colLocal);
                        }
            }
            __syncthreads();
            // interleaved 8-elem chunks: bank = (srow + scg*8 + c)%32 -> 2-way
            const u32* Sr = &S[srow * 129 + scg * 8];
            #pragma unroll
            for (int ch = 0; ch < 4; ch++) {
                #pragma unroll
                for (int c = 0; c < 8; c++) {
                    u32 x = Sr[ch * 32 + c];
                    v[h][5] = max(v[h][5], min(v[h][4], x));
                    v[h][4] = max(v[h][4], min(v[h][3], x));
                    v[h][3] = max(v[h][3], min(v[h][2], x));
                    v[h][2] = max(v[h][2], min(v[h][1], x));
                    v[h][1] = max(v[h][1], min(v[h][0], x));
                    v[h][0] = max(v[h][0], x);
                }
            }
        }
    }
    // merge the four column-group lists per row through LDS, per row-half
    #pragma unroll
    for (int h = 0; h < 2; h++) {
        __syncthreads();
        {
            u32* dst = &S[srow * 129 + scg * 6];
            #pragma unroll
            for (int j = 0; j < 6; j++) dst[j] = v[h][j];
        }
        __syncthreads();
        if (tid < 64) {
            u32 m0v = 0, m1v = 0, m2v = 0, m3v = 0, m4v = 0, m5v = 0;
            const u32* Sr = &S[tid * 129];
            #pragma unroll
            for (int s = 0; s < 24; s++) {
                u32 x = Sr[s];
                m5v = max(m5v, min(m4v, x));
                m4v = max(m4v, min(m3v, x));
                m3v = max(m3v, min(m2v, x));
                m2v = max(m2v, min(m1v, x));
                m1v = max(m1v, min(m0v, x));
                m0v = max(m0v, x);
            }
            u32* dst = tvp + (size_t)(m0 + h * 64 + tid) * 192 + bx * 6;
            dst[0] = m0v; dst[1] = m1v; dst[2] = m2v;
            dst[3] = m3v; dst[4] = m4v; dst[5] = m5v;
        }
    }
}

// merge 32 packed partial top-6 lists per row -> final top-6 (fp32 val + idx)
__global__ void topk_merge(const u32* __restrict__ tvp,
                           float* __restrict__ tv, int* __restrict__ ti)
{
    int r = blockIdx.x * 64 + threadIdx.x;
    u32 v[6]; int ix[6];
    #pragma unroll
    for (int j = 0; j < 6; j++) { v[j] = 0; ix[j] = 0; }
    const u32* pv = tvp + (size_t)r * 192;
    for (int b = 0; b < 32; b++) {
        #pragma unroll
        for (int j2 = 0; j2 < 6; j2++) {
            u32 p = pv[b * 6 + j2];
            if (p <= v[5]) break;     // group is descending: rest can't insert
            v[5] = p; ix[5] = b * 256 + 255 - (int)(p & 255u);
            #pragma unroll
            for (int j = 5; j > 0; j--) {
                if (v[j] > v[j - 1]) {
                    u32 tf = v[j]; v[j] = v[j - 1]; v[j - 1] = tf;
                    int tx = ix[j]; ix[j] = ix[j - 1]; ix[j - 1] = tx;
                }
            }
        }
    }
    #pragma unroll
    for (int j = 0; j < 6; j++) {
        tv[(size_t)r * 6 + j] = unpack_v(v[j]) * SCALE_F;
        ti[(size_t)r * 6 + j] = ix[j];
    }
}

// ---------------------------------------------------------------------------
// neighbor aggregation, one WAVE per row (no block barriers). fp32 math.
__global__ __launch_bounds__(256) void neighbor_kernel(
    const u16* __restrict__ eH, const u16* __restrict__ eT,
    const float* __restrict__ tv, const int* __restrict__ ti,
    u16* __restrict__ s1, u16* __restrict__ s2)
{
    const int tid = threadIdx.x, wave = tid >> 6, lane = tid & 63;
    const int n = blockIdx.x * 4 + wave;
    float tw[6]; int id[6];
    #pragma unroll
    for (int j = 0; j < 6; j++) {
        tw[j] = tv[n * 6 + j];
        int t = ti[n * 6 + j];
        id[j] = ((unsigned)t < 8192u) ? t : 0;
    }
    float mx = tw[0];
    #pragma unroll
    for (int j = 1; j < 6; j++) mx = fmaxf(mx, tw[j]);
    float p[6]; float ps = 0.f;
    #pragma unroll
    for (int j = 0; j < 6; j++) { p[j] = __expf(tw[j] - mx); ps += p[j]; }
    float inv = 1.0f / ps;
    #pragma unroll
    for (int j = 0; j < 6; j++) p[j] *= inv;

    const size_t base = (size_t)n * 512 + lane * 8;
    float eh[8];
    { bh8 v = *(const bh8*)(eH + base);
      #pragma unroll
      for (int c = 0; c < 8; c++) eh[c] = (float)v[c]; }
    float nb[6][8];
    #pragma unroll
    for (int j = 0; j < 6; j++) {
        bh8 v = *(const bh8*)(eT + (size_t)id[j] * 512 + lane * 8);
        #pragma unroll
        for (int c = 0; c < 8; c++) nb[j][c] = (float)v[c];
    }
    float ka[6];
    #pragma unroll
    for (int j = 0; j < 6; j++) {
        float s = 0.f;
        #pragma unroll
        for (int c = 0; c < 8; c++) {
            float e = p[j] * nb[j][c] + (1.f - p[j]) * eh[c];
            float x = eh[c] + e;
            x = fminf(fmaxf(x, -15.f), 15.f);
            float ex = __expf(2.f * x);
            float g = 1.f - 2.f / (ex + 1.f);   // tanh
            s += nb[j][c] * g;
        }
        #pragma unroll
        for (int off = 32; off > 0; off >>= 1) s += __shfl_down(s, off);
        ka[j] = __shfl(s, 0);
    }
    float m2 = ka[0];
    #pragma unroll
    for (int j = 1; j < 6; j++) m2 = fmaxf(m2, ka[j]);
    float kp[6]; float ks = 0.f;
    #pragma unroll
    for (int j = 0; j < 6; j++) { kp[j] = __expf(ka[j] - m2); ks += kp[j]; }
    float inv2 = 1.0f / ks;
    #pragma unroll
    for (int j = 0; j < 6; j++) kp[j] *= inv2;
    bh8 o1, o2;
    #pragma unroll
    for (int c = 0; c < 8; c++) {
        float eN = 0.f;
        #pragma unroll
        for (int j = 0; j < 6; j++) eN += kp[j] * nb[j][c];
        o1[c] = (bh)(eh[c] + eN);
        o2[c] = (bh)(eh[c] * eN);
    }
    *(bh8*)(s1 + base) = o1;
    *(bh8*)(s2 + base) = o2;
}

// ---------------------------------------------------------------------------
__global__ void colsum_kernel(const u16* __restrict__ h, float* __restrict__ colsum) {
    int tid = threadIdx.x;
    int n0 = blockIdx.x * 32;
    float a0 = 0.f, a1 = 0.f;
    for (int k = 0; k < 32; k++) {
        size_t b = (size_t)(n0 + k) * 512;
        a0 += bf2f(h[b + tid]); a1 += bf2f(h[b + tid + 256]);
    }
    atomicAdd(&colsum[tid], a0);
    atomicAdd(&colsum[tid + 256], a1);
}

__global__ void meanmix_kernel(u16* __restrict__ h, const float* __restrict__ colsum) {
    size_t i = ((size_t)blockIdx.x * 256 + threadIdx.x) * 8;
    int col = (int)(i & 511);
    union { int4 v; u16 s[8]; } u;
    u.v = *(const int4*)&h[i];
    #pragma unroll
    for (int j = 0; j < 8; j++)
        u.s[j] = f2bf((bf2f(u.s[j]) + colsum[col + j] * (1.0f / 8192.0f)) * 0.5f);
    *(int4*)&h[i] = u.v;
}

// parallel softmax stats: ordered-u32 atomicMax, then atomicAdd of exp sums
__global__ void att_max(const float* __restrict__ att, u32* __restrict__ scal_u) {
    int i = blockIdx.x * 256 + threadIdx.x;
    int lane = threadIdx.x & 63;
    u32 o = ordf(att[i]);
    #pragma unroll
    for (int off = 32; off > 0; off >>= 1) o = max(o, (u32)__shfl_down((int)o, off));
    if (lane == 0) atomicMax(&scal_u[0], o);
}
__global__ void att_sum(const float* __restrict__ att, float* __restrict__ scal) {
    int i = blockIdx.x * 256 + threadIdx.x;
    int lane = threadIdx.x & 63;
    float mx = unordf(((const u32*)scal)[0]);
    float e = __expf(att[i] - mx);
    #pragma unroll
    for (int off = 32; off > 0; off >>= 1) e += __shfl_down(e, off);
    if (lane == 0) atomicAdd(&scal[1], e);
}

__global__ void pooled_kernel(const u16* __restrict__ emb, const float* __restrict__ att,
                              const float* __restrict__ scal, float* __restrict__ pooled) {
    int tid = threadIdx.x;
    int n0 = blockIdx.x * 32;
    float mx = unordf(((const u32*)scal)[0]);
    float inv = 1.0f / scal[1];
    float a0 = 0.f, a1 = 0.f;
    for (int k = 0; k < 32; k++) {
        int n = n0 + k;
        float w = __expf(att[n] - mx) * inv;
        size_t b = (size_t)n * 512;
        a0 += w * bf2f(emb[b + tid]);
        a1 += w * bf2f(emb[b + tid + 256]);
    }
    atomicAdd(&pooled[tid], a0);
    atomicAdd(&pooled[tid + 256], a1);
}

__global__ void final_kernel(const float* __restrict__ pooled,
                             const float* __restrict__ g, const float* __restrict__ bln,
                             const float* __restrict__ fcw, const float* __restrict__ fcb,
                             float* __restrict__ out) {
    __shared__ float red[256];
    int tid = threadIdx.x;
    float x0 = pooled[tid], x1 = pooled[tid + 256];
    red[tid] = x0 + x1; __syncthreads();
    for (int s = 128; s > 0; s >>= 1) { if (tid < s) red[tid] += red[tid + s]; __syncthreads(); }
    float mu = red[0] * (1.0f / 512.0f); __syncthreads();
    float d0 = x0 - mu, d1 = x1 - mu;
    red[tid] = d0 * d0 + d1 * d1; __syncthreads();
    for (int s = 128; s > 0; s >>= 1) { if (tid < s) red[tid] += red[tid + s]; __syncthreads(); }
    float var = red[0] * (1.0f / 512.0f); __syncthreads();
    float rstd = rsqrtf(var + 1e-5f);
    float l0 = d0 * rstd * g[tid]       + bln[tid];
    float l1 = d1 * rstd * g[tid + 256] + bln[tid + 256];
    red[tid] = l0 * fcw[tid * 2] + l1 * fcw[(tid + 256) * 2]; __syncthreads();
    for (int s = 128; s > 0; s >>= 1) { if (tid < s) red[tid] += red[tid + s]; __syncthreads(); }
    float o0 = red[0] + fcb[0]; __syncthreads();
    red[tid] = l0 * fcw[tid * 2 + 1] + l1 * fcw[(tid + 256) * 2 + 1]; __syncthreads();
    for (int s = 128; s > 0; s >>= 1) { if (tid < s) red[tid] += red[tid + s]; __syncthreads(); }
    float o1 = red[0] + fcb[1];
    if (tid == 0) {
        float m = fmaxf(o0, o1);
        float e0 = expf(o0 - m), e1 = expf(o1 - m);
        float se = e0 + e1;
        out[0] = o0;
        out[1] = o1;
        out[2] = e0 / se;
        out[3] = e1 / se;
        out[4] = (o0 >= o1) ? 0.0f : 1.0f;
    }
}

// ---------------------------------------------------------------------------
extern "C" void kernel_launch(void* const* d_in, const int* in_sizes, int n_in,
                              void* d_out, int out_size, void* d_ws, size_t ws_size,
                              hipStream_t stream)
{
    const float* x      = (const float*)d_in[0];
    const float* fc1_w  = (const float*)d_in[1];
    const float* fc1_b  = (const float*)d_in[2];
    const float* wh_w   = (const float*)d_in[3];
    const float* wh_b   = (const float*)d_in[4];
    const float* wt_w   = (const float*)d_in[5];
    const float* wt_b   = (const float*)d_in[6];
    const float* lin1_w = (const float*)d_in[7];
    const float* lin1_b = (const float*)d_in[8];
    const float* lin2_w = (const float*)d_in[9];
    const float* lin2_b = (const float*)d_in[10];
    const float* att1_w = (const float*)d_in[11];
    const float* att1_b = (const float*)d_in[12];
    const float* att2_w = (const float*)d_in[13];
    const float* att2_b = (const float*)d_in[14];
    const float* ln_g   = (const float*)d_in[15];
    const float* ln_b   = (const float*)d_in[16];
    const float* fc_w   = (const float*)d_in[17];
    const float* fc_b   = (const float*)d_in[18];
    float* out = (float*)d_out;
    char* ws = (char*)d_ws;

    u16*   fc1T   = (u16*)(ws + 0);
    u16*   whT    = (u16*)(ws + 1048576);
    u16*   wtT    = (u16*)(ws + 1572864);
    u16*   l1T    = (u16*)(ws + 2097152);
    u16*   l2T    = (u16*)(ws + 2621440);
    u16*   a1T    = (u16*)(ws + 3145728);
    float* tv     = (float*)(ws + 3407872);
    int*   ti     = (int*)(ws + 3604480);
    float* att    = (float*)(ws + 3801088);
    float* colsum = (float*)(ws + 3833856);
    float* pooled = (float*)(ws + 3835904);
    float* scal   = (float*)(ws + 3837952);
    u32*   tvp    = (u32*)(ws + 4194304);
    u16*   hbf    = (u16*)(ws + 14680064);   // 8 MB  [h; later s1]
    u16*   ehbf   = (u16*)(ws + 23068672);   // 8 MB  [e_h]
    u16*   etbf   = (u16*)(ws + 31457280);   // 8 MB  [e_t; later emb]
    u16*   s2bf   = (u16*)(ws + 39845888);   // 8 MB  [s2]
    u16*   xbf    = (u16*)(ws + 23068672);   // 16 MB (x bf16; dead after fc1)

    transpose_cvt<<<5760, dim3(32, 8), 0, stream>>>(
        fc1_w, fc1T, wh_w, whT, wt_w, wtT, lin1_w, l1T, lin2_w, l2T, att1_w, a1T, x, xbf);
    hipMemsetAsync(att, 0, 36928, stream);   // att (32KB) + colsum + pooled + scal

    gemm128<1, 0, 1024, 4><<<dim3(4, 64), 256, 0, stream>>>(xbf, fc1T, fc1_b, nullptr, hbf, 512);
    colsum_kernel<<<256, 256, 0, stream>>>(hbf, colsum);
    meanmix_kernel<<<2048, 256, 0, stream>>>(hbf, colsum);

    ehet128<<<dim3(8, 64), 256, 0, stream>>>(hbf, whT, wtT, wh_b, wt_b, ehbf, etbf);

    logits_topk<<<dim3(32, 64), 256, 0, stream>>>(ehbf, etbf, tvp);
    topk_merge<<<128, 64, 0, stream>>>(tvp, tv, ti);

    neighbor_kernel<<<2048, 256, 0, stream>>>(ehbf, etbf, tv, ti, hbf, s2bf);

    lin12_128<<<dim3(4, 64), 256, 0, stream>>>(hbf, l1T, lin1_b, s2bf, l2T, lin2_b, etbf);

    att12_fused<<<dim3(4, 128), 256, 0, stream>>>(etbf, a1T, att1_b, att2_w, att);
    att_max<<<32, 256, 0, stream>>>(att, (u32*)scal);
    att_sum<<<32, 256, 0, stream>>>(att, scal);
    pooled_kernel<<<256, 256, 0, stream>>>(etbf, att, scal, pooled);

    final_kernel<<<1, 256, 0, stream>>>(pooled, ln_g, ln_b, fc_w, fc_b, out);
}

// Round 11
// 326.590 us; speedup vs baseline: 1.0812x; 1.0372x over previous
//
#include <hip/hip_runtime.h>
#include <hip/hip_bf16.h>
#include <cstdint>
#include <math.h>

typedef unsigned short u16;
typedef unsigned int u32;
typedef __bf16 bh;
typedef bh bh8 __attribute__((ext_vector_type(8)));
typedef float f32x4 __attribute__((ext_vector_type(4)));

#define SCALE_F 0.04419417382415922f  // 512^-0.5

__device__ __forceinline__ float bf2f(u16 u) {
    union { float f; unsigned int i; } v; v.i = ((unsigned int)u) << 16; return v.f;
}
__device__ __forceinline__ u16 f2bf(float f) {
    __hip_bfloat16 h = __float2bfloat16(f);
    return __builtin_bit_cast(u16, h);
}
__device__ __forceinline__ bh8 ld8_f32(const float* p) {
    float4 f0 = *(const float4*)p;
    float4 f1 = *(const float4*)(p + 4);
    bh8 r;
    r[0] = (bh)f0.x; r[1] = (bh)f0.y; r[2] = (bh)f0.z; r[3] = (bh)f0.w;
    r[4] = (bh)f1.x; r[5] = (bh)f1.y; r[6] = (bh)f1.z; r[7] = (bh)f1.w;
    return r;
}

// ordered-uint transforms (monotone with float order)
__device__ __forceinline__ u32 ordf(float f) {
    u32 u = __float_as_uint(f);
    return u ^ ((u32)((int)u >> 31) | 0x80000000u);
}
__device__ __forceinline__ float unordf(u32 s) {
    u32 u = (s & 0x80000000u) ? (s ^ 0x80000000u) : ~s;
    return __uint_as_float(u);
}
// 24-bit ordered value | 8-bit inverted local col idx (tie -> smaller idx wins)
__device__ __forceinline__ u32 pack_vi(float v, int inv_idx) {
    return (ordf(v) & 0xFFFFFF00u) | (u32)inv_idx;
}
__device__ __forceinline__ float unpack_v(u32 p) {
    return unordf(p & 0xFFFFFF00u);
}

// direct global->LDS 16B per lane; lds base wave-uniform (dest = base + lane*16)
__device__ __forceinline__ void gl_lds16(const u16* g, u16* l) {
    __builtin_amdgcn_global_load_lds(
        (const __attribute__((address_space(1))) void*)g,
        (__attribute__((address_space(3))) void*)l, 16, 0, 0);
}

// bijective XCD swizzle (T1): grids with NY=64 -> each XCD owns a contiguous
// 8-row y-range, y-inner order so consecutive blocks share B panels in L2.
__device__ __forceinline__ void xcd_swz(int bid, int& x, int& y) {
    int xcd = bid & 7, idx = bid >> 3;
    x = idx >> 3;
    y = xcd * 8 + (idx & 7);
}

// ---------------------------------------------------------------------------
// 6 weight transposes (fp32 [R,C] -> bf16 [C,R]) + x fp32->bf16, one dispatch
__global__ void transpose_cvt(const float* s0, u16* d0, const float* s1, u16* d1,
                              const float* s2, u16* d2, const float* s3, u16* d3,
                              const float* s4, u16* d4, const float* s5, u16* d5,
                              const float* xs, u16* xd) {
    int b = blockIdx.x;
    if (b >= 1664) {  // cvt_x part: 4096 blocks, 8 elems/thread
        int t = threadIdx.y * 32 + threadIdx.x;
        size_t i = ((size_t)(b - 1664) * 256 + t) * 8;
        *(bh8*)(xd + i) = ld8_f32(xs + i);
        return;
    }
    __shared__ float tsh[32][33];
    const float* src; u16* dst; int R, C, tt;
    if      (b < 512)  { src = s0; dst = d0; R = 1024; C = 512; tt = b; }
    else if (b < 768)  { src = s1; dst = d1; R = 512;  C = 512; tt = b - 512; }
    else if (b < 1024) { src = s2; dst = d2; R = 512;  C = 512; tt = b - 768; }
    else if (b < 1280) { src = s3; dst = d3; R = 512;  C = 512; tt = b - 1024; }
    else if (b < 1536) { src = s4; dst = d4; R = 512;  C = 512; tt = b - 1280; }
    else               { src = s5; dst = d5; R = 512;  C = 256; tt = b - 1536; }
    int ntx = C >> 5;
    int bx = (tt % ntx) * 32, by = (tt / ntx) * 32;
    int x = threadIdx.x, y = threadIdx.y;
    for (int i = 0; i < 32; i += 8)
        tsh[y + i][x] = src[(size_t)(by + y + i) * C + bx + x];
    __syncthreads();
    for (int i = 0; i < 32; i += 8)
        dst[(size_t)(bx + y + i) * R + by + x] = f2bf(tsh[x][y + i]);
}

// ---------------------------------------------------------------------------
// R10-proven 64-row K-loop (single buffer, 2 barriers/iter). High residency
// hides the drain via cross-block TLP. Used by att12_fused.
template<int KT, int NF>
__device__ __forceinline__ void kloop64(const u16* __restrict__ Ag, const u16* __restrict__ Bg,
                                        u16* Alds, u16* Blds, f32x4 (&acc)[2][NF]) {
    const int tid = threadIdx.x;
    const int wave = tid >> 6, lane = tid & 63;
    const int lr = lane & 15, quad = lane >> 4;
    const int wm = (wave & 1) * 32, wn = (wave >> 1) * (NF * 16);
    const int r = tid >> 2;
    const int g8 = (((tid & 3) ^ ((tid >> 3) & 3))) * 8;   // swizzled k-block
    const int kbr8 = (quad ^ ((lr >> 1) & 3)) * 8;         // reader slot
    const u16* ga  = Ag + (size_t)r * KT + g8;
    const u16* gb0 = Bg + (size_t)r * KT + g8;
    const u16* gb1 = gb0 + (size_t)64 * KT;                // B rows 64..127 (NF=4)
    u16* la = Alds + wave * 512;   // wave-uniform
    u16* lb = Blds + wave * 512;
    #pragma unroll
    for (int k0 = 0; k0 < KT; k0 += 32) {
        __syncthreads();                 // prior reads done before LDS overwrite
        gl_lds16(ga + k0, la);
        gl_lds16(gb0 + k0, lb);
        if (NF == 4) gl_lds16(gb1 + k0, lb + 2048);
        __syncthreads();                 // drains vmcnt -> LDS writes visible
        bh8 af[2], bf_[NF];
        #pragma unroll
        for (int i = 0; i < 2; i++)
            af[i] = *(const bh8*)&Alds[(wm + i * 16 + lr) * 32 + kbr8];
        #pragma unroll
        for (int i = 0; i < NF; i++)
            bf_[i] = *(const bh8*)&Blds[(wn + i * 16 + lr) * 32 + kbr8];
        #pragma unroll
        for (int mi = 0; mi < 2; mi++)
            #pragma unroll
            for (int ni = 0; ni < NF; ni++)
                acc[mi][ni] = __builtin_amdgcn_mfma_f32_16x16x32_bf16(
                    af[mi], bf_[ni], acc[mi][ni], 0, 0, 0);
    }
}

// ---------------------------------------------------------------------------
// R20: fused att1+att2. att[row] = sum_col lrelu(emb@W1+b1)[row][col]*w2[col].
// att2's bias is DROPPED: softmax over rows is invariant to a constant shift.
__global__ __launch_bounds__(256) void att12_fused(
    const u16* __restrict__ A, const u16* __restrict__ B,
    const float* __restrict__ b1, const float* __restrict__ w2,
    float* __restrict__ att)
{
    __shared__ __align__(16) u16 Alds[64 * 32];
    __shared__ __align__(16) u16 Blds[64 * 32];
    const int m0 = blockIdx.y * 64, n0 = blockIdx.x * 64;
    f32x4 acc[2][2] = {};
    kloop64<512, 2>(A + (size_t)m0 * 512, B + (size_t)n0 * 512, Alds, Blds, acc);
    const int tid = threadIdx.x;
    const int wave = tid >> 6, lane = tid & 63;
    const int lr = lane & 15, quad = lane >> 4;
    const int wm = (wave & 1) * 32, wn = (wave >> 1) * 32;
    float w0  = w2[n0 + wn + lr],      w1  = w2[n0 + wn + 16 + lr];
    float bs0 = b1[n0 + wn + lr],      bs1 = b1[n0 + wn + 16 + lr];
    #pragma unroll
    for (int mi = 0; mi < 2; mi++) {
        #pragma unroll
        for (int i = 0; i < 4; i++) {
            float v0 = acc[mi][0][i] + bs0;
            v0 = (v0 > 0.0f) ? v0 : 0.01f * v0;
            float v1 = acc[mi][1][i] + bs1;
            v1 = (v1 > 0.0f) ? v1 : 0.01f * v1;
            float s = v0 * w0 + v1 * w1;
            s += __shfl_down(s, 8);
            s += __shfl_down(s, 4);
            s += __shfl_down(s, 2);
            s += __shfl_down(s, 1);
            if (lr == 0)
                atomicAdd(&att[m0 + wm + mi * 16 + quad * 4 + i], s);
        }
    }
}

// ---------------------------------------------------------------------------
// 128x128-tile K-loop with counted-vmcnt pipeline (T4): 3 LDS buffers,
// prefetch depth 2, one raw s_barrier per K-step, s_waitcnt vmcnt(4).
template<int KT>
__device__ __forceinline__ void kloop128p(const u16* __restrict__ Ag,
                                          const u16* __restrict__ Bg,
                                          u16* lds, f32x4 (&acc)[4][4]) {
    const int tid = threadIdx.x;
    const int wave = tid >> 6, lane = tid & 63;
    const int lr = lane & 15, quad = lane >> 4;
    const int wm = (wave & 1) * 64, wn = (wave >> 1) * 64;
    const int r = tid >> 2;
    const int g8 = (((tid & 3) ^ ((tid >> 3) & 3))) * 8;   // swizzled k-block
    const int kbr8 = (quad ^ ((lr >> 1) & 3)) * 8;         // reader slot
    const u16* ga0 = Ag + (size_t)r * KT + g8;
    const u16* ga1 = ga0 + (size_t)64 * KT;                // A rows 64..127
    const u16* gb0 = Bg + (size_t)r * KT + g8;
    const u16* gb1 = gb0 + (size_t)64 * KT;                // B rows 64..127
    const int wofs = wave * 512;                           // wave-uniform chunk
    constexpr int NT = KT / 32;
    gl_lds16(ga0,      lds + wofs);
    gl_lds16(ga1,      lds + wofs + 2048);
    gl_lds16(gb0,      lds + 4096 + wofs);
    gl_lds16(gb1,      lds + 4096 + wofs + 2048);
    gl_lds16(ga0 + 32, lds + 8192 + wofs);
    gl_lds16(ga1 + 32, lds + 8192 + wofs + 2048);
    gl_lds16(gb0 + 32, lds + 8192 + 4096 + wofs);
    gl_lds16(gb1 + 32, lds + 8192 + 4096 + wofs + 2048);
    #pragma unroll
    for (int t = 0; t < NT; t++) {
        if (t + 1 < NT) asm volatile("s_waitcnt vmcnt(4)" ::: "memory");
        else            asm volatile("s_waitcnt vmcnt(0)" ::: "memory");
        __builtin_amdgcn_s_barrier();    // all waves' stage(t) landed
        if (t + 2 < NT) {
            const int k2 = (t + 2) * 32;
            u16* b = lds + ((t + 2) % 3) * 8192;
            gl_lds16(ga0 + k2, b + wofs);
            gl_lds16(ga1 + k2, b + wofs + 2048);
            gl_lds16(gb0 + k2, b + 4096 + wofs);
            gl_lds16(gb1 + k2, b + 4096 + wofs + 2048);
        }
        const u16* Ab = lds + (t % 3) * 8192;
        const u16* Bb = Ab + 4096;
        bh8 af[4], bf_[4];
        #pragma unroll
        for (int i = 0; i < 4; i++) {
            af[i]  = *(const bh8*)&Ab[(wm + i * 16 + lr) * 32 + kbr8];
            bf_[i] = *(const bh8*)&Bb[(wn + i * 16 + lr) * 32 + kbr8];
        }
        __builtin_amdgcn_s_setprio(1);   // T5
        #pragma unroll
        for (int mi = 0; mi < 4; mi++)
            #pragma unroll
            for (int ni = 0; ni < 4; ni++)
                acc[mi][ni] = __builtin_amdgcn_mfma_f32_16x16x32_bf16(
                    af[mi], bf_[ni], acc[mi][ni], 0, 0, 0);
        __builtin_amdgcn_s_setprio(0);
    }
    // caller must __syncthreads() before reusing LDS.
}

template<int ACT, int F32OUT>
__device__ __forceinline__ void epilogue128(f32x4 (&acc)[4][4], const float* bias,
                                            float* Cf, u16* Cb, int N, int m0, int n0) {
    const int tid = threadIdx.x;
    const int wave = tid >> 6, lane = tid & 63;
    const int lr = lane & 15, quad = lane >> 4;
    const int wm = (wave & 1) * 64, wn = (wave >> 1) * 64;
    #pragma unroll
    for (int ni = 0; ni < 4; ni++) {
        int col = n0 + wn + ni * 16 + lr;
        float bs = bias[col];
        #pragma unroll
        for (int mi = 0; mi < 4; mi++) {
            #pragma unroll
            for (int i = 0; i < 4; i++) {
                int row = m0 + wm + mi * 16 + quad * 4 + i;
                float v = acc[mi][ni][i] + bs;
                if (ACT == 1) v = fmaxf(v, 0.0f);
                if (ACT == 2) v = (v > 0.0f) ? v : 0.01f * v;
                size_t o = (size_t)row * N + col;
                if (F32OUT) Cf[o] = v;
                else        Cb[o] = f2bf(v);
            }
        }
    }
}

// ---------------------------------------------------------------------------
// R21: fc1 with FUSED column-sum (removes colsum_kernel's 8MB re-read).
// h = relu(x@fc1+b) written bf16; per-column partial summed in-register,
// quad-reduced via shfl, one atomicAdd per column per wave (colsum pre-zeroed
// by the launcher memset; ~128 adds/column across the grid).
__global__ __launch_bounds__(256) void fc1c_128(
    const u16* __restrict__ A, const u16* __restrict__ B, const float* __restrict__ bias,
    u16* __restrict__ Cb, float* __restrict__ colsum)
{
    __shared__ __align__(16) u16 ldsbuf[3 * 8192];
    int bx, by;
    xcd_swz(blockIdx.y * 4 + blockIdx.x, bx, by);
    const int m0 = by * 128, n0 = bx * 128;
    f32x4 acc[4][4] = {};
    kloop128p<1024>(A + (size_t)m0 * 1024, B + (size_t)n0 * 1024, ldsbuf, acc);
    const int tid = threadIdx.x;
    const int wave = tid >> 6, lane = tid & 63;
    const int lr = lane & 15, quad = lane >> 4;
    const int wm = (wave & 1) * 64, wn = (wave >> 1) * 64;
    #pragma unroll
    for (int ni = 0; ni < 4; ni++) {
        int col = n0 + wn + ni * 16 + lr;
        float bs = bias[col];
        float cs = 0.f;
        #pragma unroll
        for (int mi = 0; mi < 4; mi++) {
            #pragma unroll
            for (int i = 0; i < 4; i++) {
                int row = m0 + wm + mi * 16 + quad * 4 + i;
                float v = fmaxf(acc[mi][ni][i] + bs, 0.0f);
                Cb[(size_t)row * 512 + col] = f2bf(v);
                cs += v;
            }
        }
        cs += __shfl_down(cs, 32);
        cs += __shfl_down(cs, 16);
        if (quad == 0) atomicAdd(&colsum[col], cs);
    }
}

// fused e_h / e_t on 128-tiles: grid (8, 64) XCD-swizzled; bx<4 -> wh, else wt
__global__ __launch_bounds__(256) void ehet128(
    const u16* __restrict__ A, const u16* __restrict__ Bh, const u16* __restrict__ Bt,
    const float* __restrict__ bh_, const float* __restrict__ bt_,
    u16* __restrict__ Oh, u16* __restrict__ Ot)
{
    __shared__ __align__(16) u16 ldsbuf[3 * 8192];
    int bx, by;
    xcd_swz(blockIdx.y * 8 + blockIdx.x, bx, by);
    const int m0 = by * 128, n0 = (bx & 3) * 128;
    const u16* B = (bx < 4) ? Bh : Bt;
    const float* bias = (bx < 4) ? bh_ : bt_;
    u16* O = (bx < 4) ? Oh : Ot;
    f32x4 acc[4][4] = {};
    kloop128p<512>(A + (size_t)m0 * 512, B + (size_t)n0 * 512, ldsbuf, acc);
    epilogue128<0, 0>(acc, bias, nullptr, O, 512, m0, n0);
}

// ---------------------------------------------------------------------------
// R17: fused emb = lrelu(s1@l1+b1) + lrelu(s2@l2+b2) on 128-tiles: two
// sequential counted-vmcnt kloops sharing the staging LDS.
__global__ __launch_bounds__(256) void lin12_128(
    const u16* __restrict__ A1, const u16* __restrict__ B1, const float* __restrict__ b1,
    const u16* __restrict__ A2, const u16* __restrict__ B2, const float* __restrict__ b2,
    u16* __restrict__ O)
{
    __shared__ __align__(16) u16 ldsbuf[3 * 8192];
    int bx, by;
    xcd_swz(blockIdx.y * 4 + blockIdx.x, bx, by);
    const int m0 = by * 128, n0 = bx * 128;
    f32x4 acc1[4][4] = {}, acc2[4][4] = {};
    kloop128p<512>(A1 + (size_t)m0 * 512, B1 + (size_t)n0 * 512, ldsbuf, acc1);
    __syncthreads();   // kloop1 reads done before kloop2 prologue restages buf0
    kloop128p<512>(A2 + (size_t)m0 * 512, B2 + (size_t)n0 * 512, ldsbuf, acc2);
    const int tid = threadIdx.x;
    const int wave = tid >> 6, lane = tid & 63;
    const int lr = lane & 15, quad = lane >> 4;
    const int wm = (wave & 1) * 64, wn = (wave >> 1) * 64;
    #pragma unroll
    for (int ni = 0; ni < 4; ni++) {
        int col = n0 + wn + ni * 16 + lr;
        float bs1 = b1[col], bs2 = b2[col];
        #pragma unroll
        for (int mi = 0; mi < 4; mi++) {
            #pragma unroll
            for (int i = 0; i < 4; i++) {
                int row = m0 + wm + mi * 16 + quad * 4 + i;
                float v1 = acc1[mi][ni][i] + bs1;
                v1 = (v1 > 0.0f) ? v1 : 0.01f * v1;
                float v2 = acc2[mi][ni][i] + bs2;
                v2 = (v2 > 0.0f) ? v2 : 0.01f * v2;
                O[(size_t)row * 512 + col] = f2bf(v1 + v2);
            }
        }
    }
}

// ---------------------------------------------------------------------------
// R14 (best-measured): fused 128x256 logits K-loop. ONE kloop per block,
// 32 MFMA per barrier, counted vmcnt(6), 3 x 24KB buffers, depth-2 prefetch.
template<int KT>
__device__ __forceinline__ void kloop256w(const u16* __restrict__ Ag,
                                          const u16* __restrict__ Bg,
                                          u16* lds, f32x4 (&acc)[4][8]) {
    const int tid = threadIdx.x;
    const int wave = tid >> 6, lane = tid & 63;
    const int lr = lane & 15, quad = lane >> 4;
    const int wm = (wave & 1) * 64;
    const int r = tid >> 2;
    const int g8 = (((tid & 3) ^ ((tid >> 3) & 3))) * 8;   // swizzled k-block
    const int kbr8 = (quad ^ ((lr >> 1) & 3)) * 8;         // reader slot
    const u16* ga0 = Ag + (size_t)r * KT + g8;
    const u16* ga1 = ga0 + (size_t)64 * KT;
    const u16* gb0 = Bg + (size_t)r * KT + g8;
    const u16* gb1 = gb0 + (size_t)64 * KT;
    const u16* gb2 = gb0 + (size_t)128 * KT;
    const u16* gb3 = gb0 + (size_t)192 * KT;
    const int wofs = wave * 512;                           // wave-uniform chunk
    constexpr int NT = KT / 32;
    constexpr int BUF = 12288;   // u16 per buffer: A[0,4K) B0[4K,8K) B1[8K,12K)
    auto stage = [&](int t, int koff) {
        u16* b = lds + (t % 3) * BUF;
        gl_lds16(ga0 + koff, b + wofs);
        gl_lds16(ga1 + koff, b + wofs + 2048);
        gl_lds16(gb0 + koff, b + 4096 + wofs);
        gl_lds16(gb1 + koff, b + 4096 + wofs + 2048);
        gl_lds16(gb2 + koff, b + 8192 + wofs);
        gl_lds16(gb3 + koff, b + 8192 + wofs + 2048);
    };
    stage(0, 0);
    stage(1, 32);
    #pragma unroll
    for (int t = 0; t < NT; t++) {
        if (t + 1 < NT) asm volatile("s_waitcnt vmcnt(6)" ::: "memory");
        else            asm volatile("s_waitcnt vmcnt(0)" ::: "memory");
        __builtin_amdgcn_s_barrier();    // all waves' stage(t) landed
        if (t + 2 < NT) stage(t + 2, (t + 2) * 32);
        const u16* Ab = lds + (t % 3) * BUF;
        const u16* Bb = Ab + 4096 + (wave >> 1) * 4096;    // B0 or B1
        bh8 af[4];
        #pragma unroll
        for (int i = 0; i < 4; i++)
            af[i] = *(const bh8*)&Ab[(wm + i * 16 + lr) * 32 + kbr8];
        __builtin_amdgcn_s_setprio(1);   // T5
        #pragma unroll
        for (int g = 0; g < 2; g++) {    // two B-frag groups -> bounded VGPR
            bh8 bf_[4];
            #pragma unroll
            for (int j = 0; j < 4; j++)
                bf_[j] = *(const bh8*)&Bb[((g * 4 + j) * 16 + lr) * 32 + kbr8];
            #pragma unroll
            for (int mi = 0; mi < 4; mi++)
                #pragma unroll
                for (int j = 0; j < 4; j++)
                    acc[mi][g * 4 + j] = __builtin_amdgcn_mfma_f32_16x16x32_bf16(
                        af[mi], bf_[j], acc[mi][g * 4 + j], 0, 0, 0);
        }
        __builtin_amdgcn_s_setprio(0);
    }
    // caller must __syncthreads() before reusing LDS.
}

// fused logits GEMM + branchless packed top-6 (exact R14/R17 form, 114.5us).
// Block = 128 rows x 256 cols, grid (32, 64), XCD-swizzled. LDS = 72KB
// (3x24KB staging; 33KB top-k scratch S aliases it) -> 2 blocks/CU.
__global__ __launch_bounds__(256, 2) void logits_topk(
    const u16* __restrict__ Ah, const u16* __restrict__ Bt, u32* __restrict__ tvp)
{
    __shared__ __align__(16) u16 ldsbuf[3 * 12288];   // 72KB
    u32* S = (u32*)ldsbuf;                            // 64*129*4 = 33KB alias
    const int tid = threadIdx.x;
    int bx, by;
    xcd_swz(blockIdx.y * 32 + blockIdx.x, bx, by);
    const int m0 = by * 128;
    const int cb0 = bx * 256;
    const int lane = tid & 63, wave = tid >> 6;
    const int wh = wave & 1;                     // row-half this wave owns
    const int wnh = wave >> 1;                   // col-half this wave owns
    const int lr = lane & 15, quad = lane >> 4;
    const int srow = tid >> 2, scg = tid & 3;    // scan: 64 rows x 4 col-groups

    f32x4 acc[4][8] = {};
    kloop256w<512>(Ah + (size_t)m0 * 512, Bt + (size_t)cb0 * 512, ldsbuf, acc);

    u32 v[2][6] = {{0,0,0,0,0,0},{0,0,0,0,0,0}};
    #pragma unroll
    for (int h = 0; h < 2; h++) {
        #pragma unroll
        for (int nh = 0; nh < 2; nh++) {
            __syncthreads();          // kloop / prior scan reads fully done
            if (wh == h && wnh == nh) {
                #pragma unroll
                for (int mi = 0; mi < 4; mi++)
                    #pragma unroll
                    for (int f = 0; f < 8; f++)
                        #pragma unroll
                        for (int i = 0; i < 4; i++) {
                            int colLocal = nh * 128 + f * 16 + lr;
                            S[(mi * 16 + quad * 4 + i) * 129 + f * 16 + lr]
                                = pack_vi(acc[mi][f][i], 255 - colLocal);
                        }
            }
            __syncthreads();
            // interleaved 8-elem chunks: bank = (srow + scg*8 + c)%32 -> 2-way
            const u32* Sr = &S[srow * 129 + scg * 8];
            #pragma unroll
            for (int ch = 0; ch < 4; ch++) {
                #pragma unroll
                for (int c = 0; c < 8; c++) {
                    u32 x = Sr[ch * 32 + c];
                    v[h][5] = max(v[h][5], min(v[h][4], x));
                    v[h][4] = max(v[h][4], min(v[h][3], x));
                    v[h][3] = max(v[h][3], min(v[h][2], x));
                    v[h][2] = max(v[h][2], min(v[h][1], x));
                    v[h][1] = max(v[h][1], min(v[h][0], x));
                    v[h][0] = max(v[h][0], x);
                }
            }
        }
    }
    // merge the four column-group lists per row through LDS, per row-half
    #pragma unroll
    for (int h = 0; h < 2; h++) {
        __syncthreads();
        {
            u32* dst = &S[srow * 129 + scg * 6];
            #pragma unroll
            for (int j = 0; j < 6; j++) dst[j] = v[h][j];
        }
        __syncthreads();
        if (tid < 64) {
            u32 m0v = 0, m1v = 0, m2v = 0, m3v = 0, m4v = 0, m5v = 0;
            const u32* Sr = &S[tid * 129];
            #pragma unroll
            for (int s = 0; s < 24; s++) {
                u32 x = Sr[s];
                m5v = max(m5v, min(m4v, x));
                m4v = max(m4v, min(m3v, x));
                m3v = max(m3v, min(m2v, x));
                m2v = max(m2v, min(m1v, x));
                m1v = max(m1v, min(m0v, x));
                m0v = max(m0v, x);
            }
            u32* dst = tvp + (size_t)(m0 + h * 64 + tid) * 192 + bx * 6;
            dst[0] = m0v; dst[1] = m1v; dst[2] = m2v;
            dst[3] = m3v; dst[4] = m4v; dst[5] = m5v;
        }
    }
}

// merge 32 packed partial top-6 lists per row -> final top-6 (fp32 val + idx)
__global__ void topk_merge(const u32* __restrict__ tvp,
                           float* __restrict__ tv, int* __restrict__ ti)
{
    int r = blockIdx.x * 64 + threadIdx.x;
    u32 v[6]; int ix[6];
    #pragma unroll
    for (int j = 0; j < 6; j++) { v[j] = 0; ix[j] = 0; }
    const u32* pv = tvp + (size_t)r * 192;
    for (int b = 0; b < 32; b++) {
        #pragma unroll
        for (int j2 = 0; j2 < 6; j2++) {
            u32 p = pv[b * 6 + j2];
            if (p <= v[5]) break;     // group is descending: rest can't insert
            v[5] = p; ix[5] = b * 256 + 255 - (int)(p & 255u);
            #pragma unroll
            for (int j = 5; j > 0; j--) {
                if (v[j] > v[j - 1]) {
                    u32 tf = v[j]; v[j] = v[j - 1]; v[j - 1] = tf;
                    int tx = ix[j]; ix[j] = ix[j - 1]; ix[j - 1] = tx;
                }
            }
        }
    }
    #pragma unroll
    for (int j = 0; j < 6; j++) {
        tv[(size_t)r * 6 + j] = unpack_v(v[j]) * SCALE_F;
        ti[(size_t)r * 6 + j] = ix[j];
    }
}

// ---------------------------------------------------------------------------
// neighbor aggregation, one WAVE per row (no block barriers). fp32 math.
__global__ __launch_bounds__(256) void neighbor_kernel(
    const u16* __restrict__ eH, const u16* __restrict__ eT,
    const float* __restrict__ tv, const int* __restrict__ ti,
    u16* __restrict__ s1, u16* __restrict__ s2)
{
    const int tid = threadIdx.x, wave = tid >> 6, lane = tid & 63;
    const int n = blockIdx.x * 4 + wave;
    float tw[6]; int id[6];
    #pragma unroll
    for (int j = 0; j < 6; j++) {
        tw[j] = tv[n * 6 + j];
        int t = ti[n * 6 + j];
        id[j] = ((unsigned)t < 8192u) ? t : 0;
    }
    float mx = tw[0];
    #pragma unroll
    for (int j = 1; j < 6; j++) mx = fmaxf(mx, tw[j]);
    float p[6]; float ps = 0.f;
    #pragma unroll
    for (int j = 0; j < 6; j++) { p[j] = __expf(tw[j] - mx); ps += p[j]; }
    float inv = 1.0f / ps;
    #pragma unroll
    for (int j = 0; j < 6; j++) p[j] *= inv;

    const size_t base = (size_t)n * 512 + lane * 8;
    float eh[8];
    { bh8 v = *(const bh8*)(eH + base);
      #pragma unroll
      for (int c = 0; c < 8; c++) eh[c] = (float)v[c]; }
    float nb[6][8];
    #pragma unroll
    for (int j = 0; j < 6; j++) {
        bh8 v = *(const bh8*)(eT + (size_t)id[j] * 512 + lane * 8);
        #pragma unroll
        for (int c = 0; c < 8; c++) nb[j][c] = (float)v[c];
    }
    float ka[6];
    #pragma unroll
    for (int j = 0; j < 6; j++) {
        float s = 0.f;
        #pragma unroll
        for (int c = 0; c < 8; c++) {
            float e = p[j] * nb[j][c] + (1.f - p[j]) * eh[c];
            float x = eh[c] + e;
            x = fminf(fmaxf(x, -15.f), 15.f);
            float ex = __expf(2.f * x);
            float g = 1.f - 2.f / (ex + 1.f);   // tanh
            s += nb[j][c] * g;
        }
        #pragma unroll
        for (int off = 32; off > 0; off >>= 1) s += __shfl_down(s, off);
        ka[j] = __shfl(s, 0);
    }
    float m2 = ka[0];
    #pragma unroll
    for (int j = 1; j < 6; j++) m2 = fmaxf(m2, ka[j]);
    float kp[6]; float ks = 0.f;
    #pragma unroll
    for (int j = 0; j < 6; j++) { kp[j] = __expf(ka[j] - m2); ks += kp[j]; }
    float inv2 = 1.0f / ks;
    #pragma unroll
    for (int j = 0; j < 6; j++) kp[j] *= inv2;
    bh8 o1, o2;
    #pragma unroll
    for (int c = 0; c < 8; c++) {
        float eN = 0.f;
        #pragma unroll
        for (int j = 0; j < 6; j++) eN += kp[j] * nb[j][c];
        o1[c] = (bh)(eh[c] + eN);
        o2[c] = (bh)(eh[c] * eN);
    }
    *(bh8*)(s1 + base) = o1;
    *(bh8*)(s2 + base) = o2;
}

// ---------------------------------------------------------------------------
__global__ void meanmix_kernel(u16* __restrict__ h, const float* __restrict__ colsum) {
    size_t i = ((size_t)blockIdx.x * 256 + threadIdx.x) * 8;
    int col = (int)(i & 511);
    union { int4 v; u16 s[8]; } u;
    u.v = *(const int4*)&h[i];
    #pragma unroll
    for (int j = 0; j < 8; j++)
        u.s[j] = f2bf((bf2f(u.s[j]) + colsum[col + j] * (1.0f / 8192.0f)) * 0.5f);
    *(int4*)&h[i] = u.v;
}

// R21: single-block softmax stats over 8192 att values (replaces att_max +
// att_sum: one launch instead of two, one read instead of two). Writes the
// same contract: scal[0] = ordf(max) as u32, scal[1] = sum of exp(v - max).
__global__ __launch_bounds__(1024) void att_stats(
    const float* __restrict__ att, float* __restrict__ scal)
{
    __shared__ float red[16];
    const int tid = threadIdx.x;
    const int wave = tid >> 6, lane = tid & 63;
    float4 a = ((const float4*)att)[tid * 2];
    float4 b = ((const float4*)att)[tid * 2 + 1];
    float mx = fmaxf(fmaxf(fmaxf(a.x, a.y), fmaxf(a.z, a.w)),
                     fmaxf(fmaxf(b.x, b.y), fmaxf(b.z, b.w)));
    #pragma unroll
    for (int off = 32; off > 0; off >>= 1) mx = fmaxf(mx, __shfl_down(mx, off));
    if (lane == 0) red[wave] = mx;
    __syncthreads();
    if (tid == 0) {
        float m = red[0];
        #pragma unroll
        for (int w = 1; w < 16; w++) m = fmaxf(m, red[w]);
        red[0] = m;
    }
    __syncthreads();
    mx = red[0];
    float s = __expf(a.x - mx) + __expf(a.y - mx) + __expf(a.z - mx) + __expf(a.w - mx)
            + __expf(b.x - mx) + __expf(b.y - mx) + __expf(b.z - mx) + __expf(b.w - mx);
    #pragma unroll
    for (int off = 32; off > 0; off >>= 1) s += __shfl_down(s, off);
    __syncthreads();
    if (lane == 0) red[wave] = s;
    __syncthreads();
    if (tid == 0) {
        float t = 0.f;
        #pragma unroll
        for (int w = 0; w < 16; w++) t += red[w];
        ((u32*)scal)[0] = ordf(mx);
        scal[1] = t;
    }
}

__global__ void pooled_kernel(const u16* __restrict__ emb, const float* __restrict__ att,
                              const float* __restrict__ scal, float* __restrict__ pooled) {
    int tid = threadIdx.x;
    int n0 = blockIdx.x * 32;
    float mx = unordf(((const u32*)scal)[0]);
    float inv = 1.0f / scal[1];
    float a0 = 0.f, a1 = 0.f;
    for (int k = 0; k < 32; k++) {
        int n = n0 + k;
        float w = __expf(att[n] - mx) * inv;
        size_t b = (size_t)n * 512;
        a0 += w * bf2f(emb[b + tid]);
        a1 += w * bf2f(emb[b + tid + 256]);
    }
    atomicAdd(&pooled[tid], a0);
    atomicAdd(&pooled[tid + 256], a1);
}

__global__ void final_kernel(const float* __restrict__ pooled,
                             const float* __restrict__ g, const float* __restrict__ bln,
                             const float* __restrict__ fcw, const float* __restrict__ fcb,
                             float* __restrict__ out) {
    __shared__ float red[256];
    int tid = threadIdx.x;
    float x0 = pooled[tid], x1 = pooled[tid + 256];
    red[tid] = x0 + x1; __syncthreads();
    for (int s = 128; s > 0; s >>= 1) { if (tid < s) red[tid] += red[tid + s]; __syncthreads(); }
    float mu = red[0] * (1.0f / 512.0f); __syncthreads();
    float d0 = x0 - mu, d1 = x1 - mu;
    red[tid] = d0 * d0 + d1 * d1; __syncthreads();
    for (int s = 128; s > 0; s >>= 1) { if (tid < s) red[tid] += red[tid + s]; __syncthreads(); }
    float var = red[0] * (1.0f / 512.0f); __syncthreads();
    float rstd = rsqrtf(var + 1e-5f);
    float l0 = d0 * rstd * g[tid]       + bln[tid];
    float l1 = d1 * rstd * g[tid + 256] + bln[tid + 256];
    red[tid] = l0 * fcw[tid * 2] + l1 * fcw[(tid + 256) * 2]; __syncthreads();
    for (int s = 128; s > 0; s >>= 1) { if (tid < s) red[tid] += red[tid + s]; __syncthreads(); }
    float o0 = red[0] + fcb[0]; __syncthreads();
    red[tid] = l0 * fcw[tid * 2 + 1] + l1 * fcw[(tid + 256) * 2 + 1]; __syncthreads();
    for (int s = 128; s > 0; s >>= 1) { if (tid < s) red[tid] += red[tid + s]; __syncthreads(); }
    float o1 = red[0] + fcb[1];
    if (tid == 0) {
        float m = fmaxf(o0, o1);
        float e0 = expf(o0 - m), e1 = expf(o1 - m);
        float se = e0 + e1;
        out[0] = o0;
        out[1] = o1;
        out[2] = e0 / se;
        out[3] = e1 / se;
        out[4] = (o0 >= o1) ? 0.0f : 1.0f;
    }
}

// ---------------------------------------------------------------------------
extern "C" void kernel_launch(void* const* d_in, const int* in_sizes, int n_in,
                              void* d_out, int out_size, void* d_ws, size_t ws_size,
                              hipStream_t stream)
{
    const float* x      = (const float*)d_in[0];
    const float* fc1_w  = (const float*)d_in[1];
    const float* fc1_b  = (const float*)d_in[2];
    const float* wh_w   = (const float*)d_in[3];
    const float* wh_b   = (const float*)d_in[4];
    const float* wt_w   = (const float*)d_in[5];
    const float* wt_b   = (const float*)d_in[6];
    const float* lin1_w = (const float*)d_in[7];
    const float* lin1_b = (const float*)d_in[8];
    const float* lin2_w = (const float*)d_in[9];
    const float* lin2_b = (const float*)d_in[10];
    const float* att1_w = (const float*)d_in[11];
    const float* att1_b = (const float*)d_in[12];
    const float* att2_w = (const float*)d_in[13];
    const float* att2_b = (const float*)d_in[14];
    const float* ln_g   = (const float*)d_in[15];
    const float* ln_b   = (const float*)d_in[16];
    const float* fc_w   = (const float*)d_in[17];
    const float* fc_b   = (const float*)d_in[18];
    float* out = (float*)d_out;
    char* ws = (char*)d_ws;

    u16*   fc1T   = (u16*)(ws + 0);
    u16*   whT    = (u16*)(ws + 1048576);
    u16*   wtT    = (u16*)(ws + 1572864);
    u16*   l1T    = (u16*)(ws + 2097152);
    u16*   l2T    = (u16*)(ws + 2621440);
    u16*   a1T    = (u16*)(ws + 3145728);
    float* tv     = (float*)(ws + 3407872);
    int*   ti     = (int*)(ws + 3604480);
    float* att    = (float*)(ws + 3801088);
    float* colsum = (float*)(ws + 3833856);
    float* pooled = (float*)(ws + 3835904);
    float* scal   = (float*)(ws + 3837952);
    u32*   tvp    = (u32*)(ws + 4194304);
    u16*   hbf    = (u16*)(ws + 14680064);   // 8 MB  [h; later s1]
    u16*   ehbf   = (u16*)(ws + 23068672);   // 8 MB  [e_h]
    u16*   etbf   = (u16*)(ws + 31457280);   // 8 MB  [e_t; later emb]
    u16*   s2bf   = (u16*)(ws + 39845888);   // 8 MB  [s2]
    u16*   xbf    = (u16*)(ws + 23068672);   // 16 MB (x bf16; dead after fc1)

    transpose_cvt<<<5760, dim3(32, 8), 0, stream>>>(
        fc1_w, fc1T, wh_w, whT, wt_w, wtT, lin1_w, l1T, lin2_w, l2T, att1_w, a1T, x, xbf);
    hipMemsetAsync(att, 0, 36928, stream);   // att (32KB) + colsum + pooled + scal

    fc1c_128<<<dim3(4, 64), 256, 0, stream>>>(xbf, fc1T, fc1_b, hbf, colsum);
    meanmix_kernel<<<2048, 256, 0, stream>>>(hbf, colsum);

    ehet128<<<dim3(8, 64), 256, 0, stream>>>(hbf, whT, wtT, wh_b, wt_b, ehbf, etbf);

    logits_topk<<<dim3(32, 64), 256, 0, stream>>>(ehbf, etbf, tvp);
    topk_merge<<<128, 64, 0, stream>>>(tvp, tv, ti);

    neighbor_kernel<<<2048, 256, 0, stream>>>(ehbf, etbf, tv, ti, hbf, s2bf);

    lin12_128<<<dim3(4, 64), 256, 0, stream>>>(hbf, l1T, lin1_b, s2bf, l2T, lin2_b, etbf);

    att12_fused<<<dim3(4, 128), 256, 0, stream>>>(etbf, a1T, att1_b, att2_w, att);
    att_stats<<<1, 1024, 0, stream>>>(att, scal);
    pooled_kernel<<<256, 256, 0, stream>>>(etbf, att, scal, pooled);

    final_kernel<<<1, 256, 0, stream>>>(pooled, ln_g, ln_b, fc_w, fc_b, out);
}